// Round 9
// baseline (30728.650 us; speedup 1.0000x reference)
//
#include <hip/hip_runtime.h>

#define BATCH 64
#define SEQT  2048
#define DIM   256   // INPUT_SIZE
#define HID   256   // HIDDEN_SIZE
#define NG    4     // chain groups (blocks for MFMA rnn)
#define GC    16    // chains per group
#define TCH   8     // t-steps per xproj_v3 block
#define HSTR  264   // h_lds chain-row stride in f16 elems (528 B: 16B-aligned, 2-way banks)

typedef _Float16 half_t;
typedef _Float16 half2_t __attribute__((ext_vector_type(2)));
typedef _Float16 half4_t __attribute__((ext_vector_type(4)));
typedef _Float16 half8_t __attribute__((ext_vector_type(8)));
typedef float    float4_t __attribute__((ext_vector_type(4)));

__device__ __forceinline__ half8_t cvt8(float4_t a, float4_t b) {
  half8_t r;
  r[0] = (half_t)a[0]; r[1] = (half_t)a[1]; r[2] = (half_t)a[2]; r[3] = (half_t)a[3];
  r[4] = (half_t)b[0]; r[5] = (half_t)b[1]; r[6] = (half_t)b[2]; r[7] = (half_t)b[3];
  return r;
}
#define H2X(v, c) __builtin_shufflevector((v), (v), 2*(c), 2*(c)+1)

template<int CTRL>
__device__ __forceinline__ float dpp_mov(float a) {
  int t = __builtin_amdgcn_mov_dpp(__builtin_bit_cast(int, a), CTRL, 0xF, 0xF, true);
  return __builtin_bit_cast(float, t);
}

#define RNN_BAR() asm volatile("s_waitcnt lgkmcnt(0)\n\ts_barrier" ::: "memory")

// ===========================================================================
// PRIMARY PATH (needs ws >= 64MB for xpT)
// xpT layout: [g][t][c][n] f16, elem off = ((g*SEQT+t)*GC + c)*HID + n
// ===========================================================================

// ---------------------------------------------------------------------------
// xproj_v3: xp[n][c] = sum_k Wxh[n,k]*x[c,t,k] + b[n]  (A=W_xh, B=X^T).
// grid (NG, SEQT/TCH), 512 thr = 8 waves; wave owns nt = 2w,2w+1 (A stationary
// 64 VGPR).  D lane (q=l>>4, s=l&15): rows n=16nt+4q+r, col chain=s ->
// half4 b64 stores to xpT, coalesced 32B segments.
// ---------------------------------------------------------------------------
__global__ __launch_bounds__(512, 1) void xproj_v3(
    const float* __restrict__ x, const float* __restrict__ Wxh,
    const float* __restrict__ bh, half_t* __restrict__ xpT)
{
  const int l = threadIdx.x & 63;
  const int w = threadIdx.x >> 6;    // 0..7
  const int s = l & 15;
  const int q = l >> 4;
  const int g = blockIdx.x;
  const int t0 = blockIdx.y * TCH;
  const long b0 = (long)g * GC;

  half8_t aw[2][8];
  #pragma unroll
  for (int i = 0; i < 2; ++i) {
    const float* wr = Wxh + (long)((w * 2 + i) * 16 + s) * DIM + q * 8;
    #pragma unroll
    for (int kf = 0; kf < 8; ++kf) {
      float4_t v0 = *(const float4_t*)(wr + kf * 32);
      float4_t v1 = *(const float4_t*)(wr + kf * 32 + 4);
      aw[i][kf] = cvt8(v0, v1);
    }
  }
  float4_t bia[2];
  #pragma unroll
  for (int i = 0; i < 2; ++i)
    bia[i] = *(const float4_t*)(bh + (w * 2 + i) * 16 + q * 4);

  #pragma unroll 1
  for (int tt = 0; tt < TCH; ++tt) {
    const int t = t0 + tt;
    half8_t bx[8];
    const float* xr = x + ((b0 + s) * (long)SEQT + t) * DIM + q * 8;
    #pragma unroll
    for (int kf = 0; kf < 8; ++kf) {
      float4_t v0 = *(const float4_t*)(xr + kf * 32);
      float4_t v1 = *(const float4_t*)(xr + kf * 32 + 4);
      bx[kf] = cvt8(v0, v1);
    }
    #pragma unroll
    for (int i = 0; i < 2; ++i) {
      float4_t acc = bia[i];
      #pragma unroll
      for (int kf = 0; kf < 8; ++kf)
        acc = __builtin_amdgcn_mfma_f32_16x16x32_f16(aw[i][kf], bx[kf], acc, 0, 0, 0);
      half4_t h4;
      h4[0] = (half_t)acc[0]; h4[1] = (half_t)acc[1];
      h4[2] = (half_t)acc[2]; h4[3] = (half_t)acc[3];
      long off = (((long)g * SEQT + t) * GC + s) * HID + (w * 2 + i) * 16 + q * 4;
      *(half4_t*)(xpT + off) = h4;
    }
  }
}

// ---------------------------------------------------------------------------
// rnn_mfma: h_t = relu(xp_t + W_hh h_{t-1}) for 16 chains/block, 4 blocks.
// 256 thr = 4 waves; wave owns nt = 4w..4w+3 (A = W_hh rows, 128 VGPR f16,
// loaded once).  Per step:
//   B-frags = h_{t-1} from hlds (8 ds_read_b128/lane),
//   C-in    = xp (half4 b64 loads from xpT, 2-step prefetch, cvt->f32),
//   32 MFMA/wave, relu, pack half4 -> 4 ds_write_b64 to hlds[nxt],
//   y_{t-1} stored to out FROM THE B-FRAG REGS (wave stores kf=2w,2w+1:
//     16 cvt + 4 dwordx4, coalesced) -- zero extra LDS, 1-step lag.
// One lgkmcnt-only barrier/step; globals (xp loads, y stores) stay in flight.
// t=0 stores zeros to out[c][0] (h_{-1}); overwritten at t=1.  Tail stores
// y_{T-1} after the loop.
// ---------------------------------------------------------------------------
#define RNN_MSTEP(U, XQ)                                                       \
  {                                                                            \
    const int t = t2 + (U);                                                    \
    /* B-frags: h_{t-1}[chain s][32kf+8q .. +8] */                             \
    half8_t bh8[8];                                                            \
    _Pragma("unroll")                                                          \
    for (int kf = 0; kf < 8; ++kf)                                             \
      bh8[kf] = *(const half8_t*)&hlds[(U)][s * HSTR + 32 * kf + 8 * q];       \
    /* C-in from prefetched xp, then refill for t+2 (same regs) */             \
    float4_t cc[4];                                                            \
    _Pragma("unroll")                                                          \
    for (int i = 0; i < 4; ++i) {                                              \
      cc[i][0] = (float)XQ[i][0]; cc[i][1] = (float)XQ[i][1];                  \
      cc[i][2] = (float)XQ[i][2]; cc[i][3] = (float)XQ[i][3];                  \
    }                                                                          \
    {                                                                          \
      const int tp = (t + 2 < T) ? (t + 2) : (T - 1);                          \
      const half_t* xb = xpg + ((long)tp * GC + s) * HID + 4 * q;              \
      XQ[0] = *(const half4_t*)(xb + (4 * w + 0) * 16);                        \
      XQ[1] = *(const half4_t*)(xb + (4 * w + 1) * 16);                        \
      XQ[2] = *(const half4_t*)(xb + (4 * w + 2) * 16);                        \
      XQ[3] = *(const half4_t*)(xb + (4 * w + 3) * 16);                        \
    }                                                                          \
    /* MFMA: acc[i] = W_hh(tile 4w+i) . h + xp */                              \
    _Pragma("unroll")                                                          \
    for (int i = 0; i < 4; ++i) {                                              \
      float4_t acc = cc[i];                                                    \
      _Pragma("unroll")                                                        \
      for (int kf = 0; kf < 8; ++kf)                                           \
        acc = __builtin_amdgcn_mfma_f32_16x16x32_f16(aw[i][kf], bh8[kf], acc, 0, 0, 0); \
      /* relu + pack + h-write: n = (4w+i)*16 + 4q + r, chain s */             \
      half4_t h4;                                                              \
      h4[0] = (half_t)fmaxf(acc[0], 0.f); h4[1] = (half_t)fmaxf(acc[1], 0.f);  \
      h4[2] = (half_t)fmaxf(acc[2], 0.f); h4[3] = (half_t)fmaxf(acc[3], 0.f);  \
      *(half4_t*)&hlds[(U) ^ 1][s * HSTR + (4 * w + i) * 16 + 4 * q] = h4;     \
    }                                                                          \
    /* y_{t-1} store from B-frags (wave's kf = 2w, 2w+1), coalesced */         \
    {                                                                          \
      const long tm1 = (t > 0) ? (t - 1) : 0;                                  \
      _Pragma("unroll")                                                        \
      for (int j = 0; j < 2; ++j) {                                            \
        const int kf = 2 * w + j;                                              \
        half8_t v = bh8[kf];                                                   \
        float* op = outg + s * (long)SEQT * HID + tm1 * HID + 32 * kf + 8 * q; \
        float4_t o0, o1;                                                       \
        o0[0] = (float)v[0]; o0[1] = (float)v[1];                              \
        o0[2] = (float)v[2]; o0[3] = (float)v[3];                              \
        o1[0] = (float)v[4]; o1[1] = (float)v[5];                              \
        o1[2] = (float)v[6]; o1[3] = (float)v[7];                              \
        *(float4_t*)op = o0;                                                   \
        *(float4_t*)(op + 4) = o1;                                             \
      }                                                                        \
    }                                                                          \
    RNN_BAR();                                                                 \
  }

__global__ __launch_bounds__(256, 1) void rnn_mfma(
    const float* __restrict__ Whh, const half_t* __restrict__ xpT,
    float* __restrict__ out, int T)
{
  __shared__ alignas(16) half_t hlds[2][GC * HSTR];

  const int l = threadIdx.x & 63;
  const int w = threadIdx.x >> 6;   // 0..3
  const int s = l & 15;
  const int q = l >> 4;
  const int g = blockIdx.x;

  const half_t* xpg = xpT + (long)g * SEQT * GC * HID;
  float* outg = out + (long)g * GC * SEQT * HID;

  // A-frags: W_hh[16nt+s][32kf+8q .. +8], nt = 4w..4w+3 (128 VGPR)
  half8_t aw[4][8];
  #pragma unroll
  for (int i = 0; i < 4; ++i) {
    const float* wr = Whh + (long)((4 * w + i) * 16 + s) * HID + q * 8;
    #pragma unroll
    for (int kf = 0; kf < 8; ++kf) {
      float4_t v0 = *(const float4_t*)(wr + kf * 32);
      float4_t v1 = *(const float4_t*)(wr + kf * 32 + 4);
      aw[i][kf] = cvt8(v0, v1);
    }
  }

  // h_{-1} = 0 in hlds[0] (incl. pads)
  {
    half8_t z8 = {0, 0, 0, 0, 0, 0, 0, 0};
    for (int i = threadIdx.x; i < GC * HSTR / 8; i += 256)
      ((half8_t*)hlds[0])[i] = z8;
  }

  // 2-deep xp prefetch: xqa = xp[0], xqb = xp[1] (static-indexed arrays)
  half4_t xqa[4], xqb[4];
  {
    const half_t* xb0 = xpg + (0L * GC + s) * HID + 4 * q;
    const half_t* xb1 = xpg + (1L * GC + s) * HID + 4 * q;
    #pragma unroll
    for (int i = 0; i < 4; ++i) {
      xqa[i] = *(const half4_t*)(xb0 + (4 * w + i) * 16);
      xqb[i] = *(const half4_t*)(xb1 + (4 * w + i) * 16);
    }
  }
  RNN_BAR();

  #pragma unroll 1
  for (int t2 = 0; t2 < T; t2 += 2) {
    RNN_MSTEP(0, xqa)
    RNN_MSTEP(1, xqb)
  }

  // tail: y_{T-1} from hlds[0] (T even: step T-1 wrote hlds[0])
  #pragma unroll
  for (int j = 0; j < 2; ++j) {
    const int kf = 2 * w + j;
    half8_t v = *(const half8_t*)&hlds[0][s * HSTR + 32 * kf + 8 * q];
    float* op = outg + s * (long)SEQT * HID + (long)(T - 1) * HID + 32 * kf + 8 * q;
    float4_t o0, o1;
    o0[0] = (float)v[0]; o0[1] = (float)v[1]; o0[2] = (float)v[2]; o0[3] = (float)v[3];
    o1[0] = (float)v[4]; o1[1] = (float)v[5]; o1[2] = (float)v[6]; o1[3] = (float)v[7];
    *(float4_t*)op = o0;
    *(float4_t*)(op + 4) = o1;
  }
}

// ===========================================================================
// FALLBACK PATH (round-6 kernels, 851us class) if ws too small for xpT
// ===========================================================================

__global__ __launch_bounds__(256) void cvt_w_kernel(
    const float* __restrict__ W, half_t* __restrict__ Wh)
{
  const int i = (blockIdx.x * 256 + threadIdx.x) * 4;
  float4_t v = *(const float4_t*)(W + i);
  half4_t o; o[0]=(half_t)v[0]; o[1]=(half_t)v[1]; o[2]=(half_t)v[2]; o[3]=(half_t)v[3];
  *(half4_t*)(Wh + i) = o;
}

__global__ __launch_bounds__(256) void xproj_f16_v2(
    const float* __restrict__ x, const half_t* __restrict__ Wh,
    const float* __restrict__ bh, float* __restrict__ out)
{
  const int lane = threadIdx.x & 63;
  const int wave = threadIdx.x >> 6;
  const int r16  = lane & 15;
  const int kg   = lane >> 4;
  const long m0  = (long)blockIdx.x * 128;

  half8_t bfr[4][8];
  float bb[4];
  #pragma unroll
  for (int qq = 0; qq < 4; ++qq) {
    const int nt = wave * 4 + qq;
    const half_t* wr = Wh + (nt * 16 + r16) * (long)DIM + kg * 8;
    #pragma unroll
    for (int kf = 0; kf < 8; ++kf)
      bfr[qq][kf] = *(const half8_t*)(wr + kf * 32);
    bb[qq] = bh[nt * 16 + r16];
  }
  #pragma unroll 1
  for (int mi = 0; mi < 8; ++mi) {
    const long mrow = m0 + mi * 16;
    half8_t a[8];
    const float* xr = x + (mrow + r16) * (long)DIM + kg * 8;
    #pragma unroll
    for (int kf = 0; kf < 8; ++kf) {
      float4_t x0 = *(const float4_t*)(xr + kf * 32);
      float4_t x1 = *(const float4_t*)(xr + kf * 32 + 4);
      a[kf] = cvt8(x0, x1);
    }
    #pragma unroll
    for (int qq = 0; qq < 4; ++qq) {
      float4_t acc = {bb[qq], bb[qq], bb[qq], bb[qq]};
      #pragma unroll
      for (int kf = 0; kf < 8; ++kf)
        acc = __builtin_amdgcn_mfma_f32_16x16x32_f16(a[kf], bfr[qq][kf], acc, 0, 0, 0);
      float* op = out + (mrow + kg * 4) * (long)HID + (wave * 4 + qq) * 16 + r16;
      #pragma unroll
      for (int r = 0; r < 4; ++r) op[(long)r * HID] = acc[r];
    }
  }
}

#define FDOT_STEP(U, XQ)                                                       \
  {                                                                            \
    const int t = t4 + (U);                                                    \
    const int tp = (t + 4 < T) ? (t + 4) : (T - 1);                            \
    float xnew = outp[(long)tp * HID];                                         \
    half8_t hv[4];                                                             \
    _Pragma("unroll")                                                          \
    for (int ss = 0; ss < 4; ++ss)                                             \
      hv[ss] = *(const half8_t*)(hraw[(U) & 1] + rb + 16 * ss);                \
    float a0 = 0.f, a1 = 0.f, a2 = 0.f, a3 = 0.f;                              \
    _Pragma("unroll")                                                          \
    for (int ss = 0; ss < 4; ++ss) {                                           \
      a0 = __builtin_amdgcn_fdot2(H2X(w8[0][ss], 0), H2X(hv[ss], 0), a0, false); \
      a0 = __builtin_amdgcn_fdot2(H2X(w8[0][ss], 1), H2X(hv[ss], 1), a0, false); \
      a0 = __builtin_amdgcn_fdot2(H2X(w8[0][ss], 2), H2X(hv[ss], 2), a0, false); \
      a0 = __builtin_amdgcn_fdot2(H2X(w8[0][ss], 3), H2X(hv[ss], 3), a0, false); \
      a1 = __builtin_amdgcn_fdot2(H2X(w8[1][ss], 0), H2X(hv[ss], 0), a1, false); \
      a1 = __builtin_amdgcn_fdot2(H2X(w8[1][ss], 1), H2X(hv[ss], 1), a1, false); \
      a1 = __builtin_amdgcn_fdot2(H2X(w8[1][ss], 2), H2X(hv[ss], 2), a1, false); \
      a1 = __builtin_amdgcn_fdot2(H2X(w8[1][ss], 3), H2X(hv[ss], 3), a1, false); \
      a2 = __builtin_amdgcn_fdot2(H2X(w8[2][ss], 0), H2X(hv[ss], 0), a2, false); \
      a2 = __builtin_amdgcn_fdot2(H2X(w8[2][ss], 1), H2X(hv[ss], 1), a2, false); \
      a2 = __builtin_amdgcn_fdot2(H2X(w8[2][ss], 2), H2X(hv[ss], 2), a2, false); \
      a2 = __builtin_amdgcn_fdot2(H2X(w8[2][ss], 3), H2X(hv[ss], 3), a2, false); \
      a3 = __builtin_amdgcn_fdot2(H2X(w8[3][ss], 0), H2X(hv[ss], 0), a3, false); \
      a3 = __builtin_amdgcn_fdot2(H2X(w8[3][ss], 1), H2X(hv[ss], 1), a3, false); \
      a3 = __builtin_amdgcn_fdot2(H2X(w8[3][ss], 2), H2X(hv[ss], 2), a3, false); \
      a3 = __builtin_amdgcn_fdot2(H2X(w8[3][ss], 3), H2X(hv[ss], 3), a3, false); \
    }                                                                          \
    float r0 = kA ? a0 : a2;                                                   \
    float r1 = kA ? a1 : a3;                                                   \
    float b0 = (kA ? a2 : a0) + dpp_mov<0x141>(r0);                            \
    float b1 = (kA ? a3 : a1) + dpp_mov<0x141>(r1);                            \
    float rB = kB ? b0 : b1;                                                   \
    float c  = (kB ? b1 : b0) + dpp_mov<0x4E>(rB);                             \
    float fin = c + dpp_mov<0xB1>(c);                                          \
    float y = fmaxf(fin + (XQ), 0.f);                                          \
    outp[(long)t * HID] = y;                                                   \
    *(half_t*)(hraw[((U) & 1) ^ 1] + hwb) = (half_t)y;                         \
    XQ = xnew;                                                                 \
    RNN_BAR();                                                                 \
  }

__global__ __launch_bounds__(512, 1) void rnn_fdot(
    const float* __restrict__ Whh, float* __restrict__ out, int T)
{
  __shared__ alignas(128) unsigned char hraw[2][8 * 80];

  const int tid = threadIdx.x;
  const int l   = tid & 63;
  const int w   = tid >> 6;
  const int g   = l & 7;
  const int j0  = w * 32 + (l >> 3) * 4;
  const int rb  = g * 80;
  const int jown = j0 + ((l >> 1) & 3);
  const int hwb = ((jown >> 5) * 80 + (jown & 31) * 2);
  const bool kA = (l & 4) != 0;
  const bool kB = (l & 2) != 0;
  float* outp = out + (long)blockIdx.x * SEQT * HID + jown;

  half8_t w8[4][4];
  #pragma unroll
  for (int i = 0; i < 4; ++i) {
    const float* wr = Whh + (long)(j0 + i) * HID + g * 32;
    #pragma unroll
    for (int ss = 0; ss < 4; ++ss) {
      float4_t v0 = *(const float4_t*)(wr + ss * 8);
      float4_t v1 = *(const float4_t*)(wr + ss * 8 + 4);
      w8[i][ss] = cvt8(v0, v1);
    }
  }
  if (tid < 160) ((float*)hraw[0])[tid] = 0.f;

  float xq0 = outp[0L * HID];
  float xq1 = outp[1L * HID];
  float xq2 = outp[2L * HID];
  float xq3 = outp[3L * HID];
  RNN_BAR();

  #pragma unroll 1
  for (int t4 = 0; t4 < T; t4 += 4) {
    FDOT_STEP(0, xq0)
    FDOT_STEP(1, xq1)
    FDOT_STEP(2, xq2)
    FDOT_STEP(3, xq3)
  }
}

// ===========================================================================
extern "C" void kernel_launch(void* const* d_in, const int* in_sizes, int n_in,
                              void* d_out, int out_size, void* d_ws, size_t ws_size,
                              hipStream_t stream) {
  const float* x   = (const float*)d_in[0];
  const float* Wxh = (const float*)d_in[1];
  const float* Whh = (const float*)d_in[2];
  const float* bh  = (const float*)d_in[3];
  float* out = (float*)d_out;

  const size_t xpt_bytes = (size_t)BATCH * SEQT * HID * sizeof(half_t);  // 64 MB
  if (ws_size >= xpt_bytes) {
    half_t* xpT = (half_t*)d_ws;
    xproj_v3<<<dim3(NG, SEQT / TCH), dim3(512), 0, stream>>>(x, Wxh, bh, xpT);
    rnn_mfma<<<dim3(NG), dim3(256), 0, stream>>>(Whh, xpT, out, SEQT);
  } else if (ws_size >= (size_t)(DIM * HID * sizeof(half_t))) {
    half_t* Wh = (half_t*)d_ws;
    cvt_w_kernel<<<dim3((DIM * HID) / 1024), dim3(256), 0, stream>>>(Wxh, Wh);
    xproj_f16_v2<<<dim3((BATCH * SEQT) / 128), dim3(256), 0, stream>>>(x, Wh, bh, out);
    rnn_fdot<<<dim3(BATCH), dim3(512), 0, stream>>>(Whh, out, SEQT);
  } else {
    // last resort: fp32-weight xproj then fdot rnn
    xproj_f16_v2<<<dim3((BATCH * SEQT) / 128), dim3(256), 0, stream>>>(
        x, (const half_t*)Wxh, bh, out);  // unreachable in practice
    rnn_fdot<<<dim3(BATCH), dim3(512), 0, stream>>>(Whh, out, SEQT);
  }
}

// Round 10
// 2510.167 us; speedup vs baseline: 12.2417x; 12.2417x over previous
//
#include <hip/hip_runtime.h>

#define BATCH 64
#define SEQT  2048
#define DIM   256   // INPUT_SIZE
#define HID   256   // HIDDEN_SIZE
#define NG    4     // chain groups (blocks for MFMA rnn)
#define GC    16    // chains per group
#define TCH   8     // t-steps per xproj_v3 block
#define HSTR  260   // hlds chain-row stride in f16 (130 words == 2 mod 32: uniform banks)

typedef _Float16 half_t;
typedef _Float16 half2_t __attribute__((ext_vector_type(2)));
typedef _Float16 half4_t __attribute__((ext_vector_type(4)));
typedef _Float16 half8_t __attribute__((ext_vector_type(8)));
typedef float    float4_t __attribute__((ext_vector_type(4)));

__device__ __forceinline__ half8_t cvt8(float4_t a, float4_t b) {
  half8_t r;
  r[0] = (half_t)a[0]; r[1] = (half_t)a[1]; r[2] = (half_t)a[2]; r[3] = (half_t)a[3];
  r[4] = (half_t)b[0]; r[5] = (half_t)b[1]; r[6] = (half_t)b[2]; r[7] = (half_t)b[3];
  return r;
}
#define H2X(v, c) __builtin_shufflevector((v), (v), 2*(c), 2*(c)+1)

template<int CTRL>
__device__ __forceinline__ float dpp_mov(float a) {
  int t = __builtin_amdgcn_mov_dpp(__builtin_bit_cast(int, a), CTRL, 0xF, 0xF, true);
  return __builtin_bit_cast(float, t);
}

#define RNN_BAR() asm volatile("s_waitcnt lgkmcnt(0)\n\ts_barrier" ::: "memory")

// ===========================================================================
// PRIMARY PATH (needs ws >= 64MB for xpT)
// xpT element offset: F(g,t,n,c) = (((g*SEQT+t)*64 + (n>>2))*GC + c)*4 + (n&3)
// -> for fixed (t, n-quad), the 16 chains x half4 are CONTIGUOUS (128 B):
//    every wave-level load/store below covers one contiguous 512 B segment.
// ===========================================================================

// ---------------------------------------------------------------------------
// xproj_v3: xp[n][c] = sum_k Wxh[n,k]*x[c,t,k] + b[n]  (A=W_xh stationary).
// grid (NG, SEQT/TCH), 512 thr = 8 waves; wave owns n-tiles nt=2w,2w+1.
// D lane (q=l>>4, s=l&15): rows n=16nt+4q+r, col chain s.
// Store half4 at F(g,t,16nt+4q,s): lanes s contiguous -> 512B/instr.
// ---------------------------------------------------------------------------
__global__ __launch_bounds__(512, 1) void xproj_v3(
    const float* __restrict__ x, const float* __restrict__ Wxh,
    const float* __restrict__ bh, half_t* __restrict__ xpT)
{
  const int l = threadIdx.x & 63;
  const int w = threadIdx.x >> 6;    // 0..7
  const int s = l & 15;
  const int q = l >> 4;
  const int g = blockIdx.x;
  const int t0 = blockIdx.y * TCH;
  const long b0 = (long)g * GC;

  half8_t aw[2][8];
  #pragma unroll
  for (int i = 0; i < 2; ++i) {
    const float* wr = Wxh + (long)((w * 2 + i) * 16 + s) * DIM + q * 8;
    #pragma unroll
    for (int kf = 0; kf < 8; ++kf) {
      float4_t v0 = *(const float4_t*)(wr + kf * 32);
      float4_t v1 = *(const float4_t*)(wr + kf * 32 + 4);
      aw[i][kf] = cvt8(v0, v1);
    }
  }
  float4_t bia[2];
  #pragma unroll
  for (int i = 0; i < 2; ++i)
    bia[i] = *(const float4_t*)(bh + (w * 2 + i) * 16 + q * 4);

  #pragma unroll 1
  for (int tt = 0; tt < TCH; ++tt) {
    const int t = t0 + tt;
    half8_t bx[8];
    const float* xr = x + ((b0 + s) * (long)SEQT + t) * DIM + q * 8;
    #pragma unroll
    for (int kf = 0; kf < 8; ++kf) {
      float4_t v0 = *(const float4_t*)(xr + kf * 32);
      float4_t v1 = *(const float4_t*)(xr + kf * 32 + 4);
      bx[kf] = cvt8(v0, v1);
    }
    #pragma unroll
    for (int i = 0; i < 2; ++i) {
      float4_t acc = bia[i];
      #pragma unroll
      for (int kf = 0; kf < 8; ++kf)
        acc = __builtin_amdgcn_mfma_f32_16x16x32_f16(aw[i][kf], bx[kf], acc, 0, 0, 0);
      half4_t h4;
      h4[0] = (half_t)acc[0]; h4[1] = (half_t)acc[1];
      h4[2] = (half_t)acc[2]; h4[3] = (half_t)acc[3];
      long off = (((long)(g * SEQT + t) * 64) + (w * 2 + i) * 4 + q) * (GC * 4) + s * 4;
      *(half4_t*)(xpT + off) = h4;
    }
  }
}

// ---------------------------------------------------------------------------
// rnn_mfma v2: h_t = relu(xp_t + W_hh h_{t-1}), 16 chains/block, 4 blocks,
// 256 thr = 4 waves; wave owns n-tiles 4w..4w+3 (A = W_hh, 128 VGPR, once).
// hlds = 4-deep ring: slot t&3 holds h_t (f16, HSTR=260 stride).
// Per step: 8 ds_read_b128 (B-frags, uniform-bank), xp C-in from 4-deep
// register prefetch (coalesced 512B loads), 32 MFMA, relu+pack, 4 ds_write_b64.
// Every 4 steps: store phase - 16 lanes/chain read hlds slots and write
// out[c][t][:] as 4x dwordx4 contiguous (1KB/chain/t).  No scattered global
// access anywhere; no per-step global stores.
// ---------------------------------------------------------------------------
#define RNN_MSTEP(U, XQ)                                                       \
  {                                                                            \
    const int t = t4 + (U);                                                    \
    /* B-frags: h_{t-1} from ring slot (U+3)&3 */                              \
    half8_t bh8[8];                                                            \
    _Pragma("unroll")                                                          \
    for (int kf = 0; kf < 8; ++kf)                                             \
      bh8[kf] = *(const half8_t*)&hlds[((U) + 3) & 3][s * HSTR + 32 * kf + 8 * q]; \
    /* C-in from prefetched xp, then refill same regs for t+4 */               \
    float4_t cc[4];                                                            \
    _Pragma("unroll")                                                          \
    for (int i = 0; i < 4; ++i) {                                              \
      cc[i][0] = (float)XQ[i][0]; cc[i][1] = (float)XQ[i][1];                  \
      cc[i][2] = (float)XQ[i][2]; cc[i][3] = (float)XQ[i][3];                  \
    }                                                                          \
    {                                                                          \
      const long tp = (t + 4 < T) ? (t + 4) : (T - 1);                         \
      _Pragma("unroll")                                                        \
      for (int i = 0; i < 4; ++i)                                              \
        XQ[i] = *(const half4_t*)(xpg +                                        \
            (tp * 64 + (4 * w + i) * 4 + q) * (GC * 4) + s * 4);               \
    }                                                                          \
    /* MFMA + relu + h-write to ring slot U */                                 \
    _Pragma("unroll")                                                          \
    for (int i = 0; i < 4; ++i) {                                              \
      float4_t acc = cc[i];                                                    \
      _Pragma("unroll")                                                        \
      for (int kf = 0; kf < 8; ++kf)                                           \
        acc = __builtin_amdgcn_mfma_f32_16x16x32_f16(aw[i][kf], bh8[kf], acc, 0, 0, 0); \
      half4_t h4;                                                              \
      h4[0] = (half_t)fmaxf(acc[0], 0.f); h4[1] = (half_t)fmaxf(acc[1], 0.f);  \
      h4[2] = (half_t)fmaxf(acc[2], 0.f); h4[3] = (half_t)fmaxf(acc[3], 0.f);  \
      *(half4_t*)&hlds[(U)][s * HSTR + (4 * w + i) * 16 + 4 * q] = h4;         \
    }                                                                          \
    RNN_BAR();                                                                 \
  }

// store phase sub-step: out rows for t = t4+tt from ring slot tt
#define RNN_YSTORE(tt)                                                         \
  {                                                                            \
    half8_t v0 = *(const half8_t*)&hlds[(tt)][c * HSTR + sub * 16];            \
    half8_t v1 = *(const half8_t*)&hlds[(tt)][c * HSTR + sub * 16 + 8];        \
    float* op = outg + (long)c * SEQT * HID + (long)(t4 + (tt)) * HID + sub * 16; \
    float4_t o;                                                                \
    o[0] = (float)v0[0]; o[1] = (float)v0[1]; o[2] = (float)v0[2]; o[3] = (float)v0[3]; \
    *(float4_t*)op = o;                                                        \
    o[0] = (float)v0[4]; o[1] = (float)v0[5]; o[2] = (float)v0[6]; o[3] = (float)v0[7]; \
    *(float4_t*)(op + 4) = o;                                                  \
    o[0] = (float)v1[0]; o[1] = (float)v1[1]; o[2] = (float)v1[2]; o[3] = (float)v1[3]; \
    *(float4_t*)(op + 8) = o;                                                  \
    o[0] = (float)v1[4]; o[1] = (float)v1[5]; o[2] = (float)v1[6]; o[3] = (float)v1[7]; \
    *(float4_t*)(op + 12) = o;                                                 \
  }

__global__ __launch_bounds__(256, 1) void rnn_mfma(
    const float* __restrict__ Whh, const half_t* __restrict__ xpT,
    float* __restrict__ out, int T)
{
  __shared__ alignas(16) half_t hlds[4][GC * HSTR];

  const int l = threadIdx.x & 63;
  const int w = threadIdx.x >> 6;   // 0..3
  const int s = l & 15;
  const int q = l >> 4;
  const int g = blockIdx.x;
  const int c   = threadIdx.x >> 4;  // store-phase chain (0..15)
  const int sub = threadIdx.x & 15;  // store-phase n-sixteenth

  const half_t* xpg = xpT + (long)g * SEQT * (GC * HID);
  float* outg = out + (long)g * GC * SEQT * HID;

  // A-frags: W_hh[16nt+s][32kf+8q .. +8], nt = 4w..4w+3 (128 VGPR)
  half8_t aw[4][8];
  #pragma unroll
  for (int i = 0; i < 4; ++i) {
    const float* wr = Whh + (long)((4 * w + i) * 16 + s) * HID + q * 8;
    #pragma unroll
    for (int kf = 0; kf < 8; ++kf) {
      float4_t v0 = *(const float4_t*)(wr + kf * 32);
      float4_t v1 = *(const float4_t*)(wr + kf * 32 + 4);
      aw[i][kf] = cvt8(v0, v1);
    }
  }

  // zero the whole ring (slot 3 = h_{-1} = 0 is what matters)
  {
    half8_t z8 = {0, 0, 0, 0, 0, 0, 0, 0};
    for (int i = threadIdx.x; i < 4 * GC * HSTR / 8; i += 256)
      ((half8_t*)hlds)[i] = z8;
  }

  // 4-deep xp prefetch: xq{0..3} hold xp for t = 0..3
  half4_t xq0[4], xq1[4], xq2[4], xq3[4];
  #pragma unroll
  for (int i = 0; i < 4; ++i) {
    const long nb = (4 * w + i) * 4 + q;
    xq0[i] = *(const half4_t*)(xpg + (0L * 64 + nb) * (GC * 4) + s * 4);
    xq1[i] = *(const half4_t*)(xpg + (1L * 64 + nb) * (GC * 4) + s * 4);
    xq2[i] = *(const half4_t*)(xpg + (2L * 64 + nb) * (GC * 4) + s * 4);
    xq3[i] = *(const half4_t*)(xpg + (3L * 64 + nb) * (GC * 4) + s * 4);
  }
  RNN_BAR();

  #pragma unroll 1
  for (int t4 = 0; t4 < T; t4 += 4) {
    RNN_MSTEP(0, xq0)
    RNN_MSTEP(1, xq1)
    RNN_MSTEP(2, xq2)
    RNN_MSTEP(3, xq3)
    // store phase: out[c][t4..t4+3][:] from ring slots 0..3 (coalesced 1KB runs)
    RNN_YSTORE(0) RNN_YSTORE(1) RNN_YSTORE(2) RNN_YSTORE(3)
    RNN_BAR();   // protect ring slots from next iteration's overwrites
  }
}

// ===========================================================================
// FALLBACK PATH (round-6 rnn @851us + B-stationary xproj) if ws < 64MB
// ===========================================================================

__global__ __launch_bounds__(256) void cvt_w_kernel(
    const float* __restrict__ W, half_t* __restrict__ Wh)
{
  const int i = (blockIdx.x * 256 + threadIdx.x) * 4;
  float4_t v = *(const float4_t*)(W + i);
  half4_t o; o[0]=(half_t)v[0]; o[1]=(half_t)v[1]; o[2]=(half_t)v[2]; o[3]=(half_t)v[3];
  *(half4_t*)(Wh + i) = o;
}

__global__ __launch_bounds__(256) void xproj_f16_v2(
    const float* __restrict__ x, const half_t* __restrict__ Wh,
    const float* __restrict__ bh, float* __restrict__ out)
{
  const int lane = threadIdx.x & 63;
  const int wave = threadIdx.x >> 6;
  const int r16  = lane & 15;
  const int kg   = lane >> 4;
  const long m0  = (long)blockIdx.x * 128;

  half8_t bfr[4][8];
  float bb[4];
  #pragma unroll
  for (int qq = 0; qq < 4; ++qq) {
    const int nt = wave * 4 + qq;
    const half_t* wr = Wh + (nt * 16 + r16) * (long)DIM + kg * 8;
    #pragma unroll
    for (int kf = 0; kf < 8; ++kf)
      bfr[qq][kf] = *(const half8_t*)(wr + kf * 32);
    bb[qq] = bh[nt * 16 + r16];
  }
  #pragma unroll 1
  for (int mi = 0; mi < 8; ++mi) {
    const long mrow = m0 + mi * 16;
    half8_t a[8];
    const float* xr = x + (mrow + r16) * (long)DIM + kg * 8;
    #pragma unroll
    for (int kf = 0; kf < 8; ++kf) {
      float4_t x0 = *(const float4_t*)(xr + kf * 32);
      float4_t x1 = *(const float4_t*)(xr + kf * 32 + 4);
      a[kf] = cvt8(x0, x1);
    }
    #pragma unroll
    for (int qq = 0; qq < 4; ++qq) {
      float4_t acc = {bb[qq], bb[qq], bb[qq], bb[qq]};
      #pragma unroll
      for (int kf = 0; kf < 8; ++kf)
        acc = __builtin_amdgcn_mfma_f32_16x16x32_f16(a[kf], bfr[qq][kf], acc, 0, 0, 0);
      float* op = out + (mrow + kg * 4) * (long)HID + (wave * 4 + qq) * 16 + r16;
      #pragma unroll
      for (int r = 0; r < 4; ++r) op[(long)r * HID] = acc[r];
    }
  }
}

#define FDOT_STEP(U, XQ)                                                       \
  {                                                                            \
    const int t = t4 + (U);                                                    \
    const int tp = (t + 4 < T) ? (t + 4) : (T - 1);                            \
    float xnew = outp[(long)tp * HID];                                         \
    half8_t hv[4];                                                             \
    _Pragma("unroll")                                                          \
    for (int ss = 0; ss < 4; ++ss)                                             \
      hv[ss] = *(const half8_t*)(hraw[(U) & 1] + rb + 16 * ss);                \
    float a0 = 0.f, a1 = 0.f, a2 = 0.f, a3 = 0.f;                              \
    _Pragma("unroll")                                                          \
    for (int ss = 0; ss < 4; ++ss) {                                           \
      a0 = __builtin_amdgcn_fdot2(H2X(w8[0][ss], 0), H2X(hv[ss], 0), a0, false); \
      a0 = __builtin_amdgcn_fdot2(H2X(w8[0][ss], 1), H2X(hv[ss], 1), a0, false); \
      a0 = __builtin_amdgcn_fdot2(H2X(w8[0][ss], 2), H2X(hv[ss], 2), a0, false); \
      a0 = __builtin_amdgcn_fdot2(H2X(w8[0][ss], 3), H2X(hv[ss], 3), a0, false); \
      a1 = __builtin_amdgcn_fdot2(H2X(w8[1][ss], 0), H2X(hv[ss], 0), a1, false); \
      a1 = __builtin_amdgcn_fdot2(H2X(w8[1][ss], 1), H2X(hv[ss], 1), a1, false); \
      a1 = __builtin_amdgcn_fdot2(H2X(w8[1][ss], 2), H2X(hv[ss], 2), a1, false); \
      a1 = __builtin_amdgcn_fdot2(H2X(w8[1][ss], 3), H2X(hv[ss], 3), a1, false); \
      a2 = __builtin_amdgcn_fdot2(H2X(w8[2][ss], 0), H2X(hv[ss], 0), a2, false); \
      a2 = __builtin_amdgcn_fdot2(H2X(w8[2][ss], 1), H2X(hv[ss], 1), a2, false); \
      a2 = __builtin_amdgcn_fdot2(H2X(w8[2][ss], 2), H2X(hv[ss], 2), a2, false); \
      a2 = __builtin_amdgcn_fdot2(H2X(w8[2][ss], 3), H2X(hv[ss], 3), a2, false); \
      a3 = __builtin_amdgcn_fdot2(H2X(w8[3][ss], 0), H2X(hv[ss], 0), a3, false); \
      a3 = __builtin_amdgcn_fdot2(H2X(w8[3][ss], 1), H2X(hv[ss], 1), a3, false); \
      a3 = __builtin_amdgcn_fdot2(H2X(w8[3][ss], 2), H2X(hv[ss], 2), a3, false); \
      a3 = __builtin_amdgcn_fdot2(H2X(w8[3][ss], 3), H2X(hv[ss], 3), a3, false); \
    }                                                                          \
    float r0 = kA ? a0 : a2;                                                   \
    float r1 = kA ? a1 : a3;                                                   \
    float b0 = (kA ? a2 : a0) + dpp_mov<0x141>(r0);                            \
    float b1 = (kA ? a3 : a1) + dpp_mov<0x141>(r1);                            \
    float rB = kB ? b0 : b1;                                                   \
    float cX = (kB ? b1 : b0) + dpp_mov<0x4E>(rB);                             \
    float fin = cX + dpp_mov<0xB1>(cX);                                        \
    float y = fmaxf(fin + (XQ), 0.f);                                          \
    outp[(long)t * HID] = y;                                                   \
    *(half_t*)(hraw[((U) & 1) ^ 1] + hwb) = (half_t)y;                         \
    XQ = xnew;                                                                 \
    RNN_BAR();                                                                 \
  }

__global__ __launch_bounds__(512, 1) void rnn_fdot(
    const float* __restrict__ Whh, float* __restrict__ out, int T)
{
  __shared__ alignas(128) unsigned char hraw[2][8 * 80];

  const int tid = threadIdx.x;
  const int l   = tid & 63;
  const int w   = tid >> 6;
  const int g   = l & 7;
  const int j0  = w * 32 + (l >> 3) * 4;
  const int rb  = g * 80;
  const int jown = j0 + ((l >> 1) & 3);
  const int hwb = ((jown >> 5) * 80 + (jown & 31) * 2);
  const bool kA = (l & 4) != 0;
  const bool kB = (l & 2) != 0;
  float* outp = out + (long)blockIdx.x * SEQT * HID + jown;

  half8_t w8[4][4];
  #pragma unroll
  for (int i = 0; i < 4; ++i) {
    const float* wr = Whh + (long)(j0 + i) * HID + g * 32;
    #pragma unroll
    for (int ss = 0; ss < 4; ++ss) {
      float4_t v0 = *(const float4_t*)(wr + ss * 8);
      float4_t v1 = *(const float4_t*)(wr + ss * 8 + 4);
      w8[i][ss] = cvt8(v0, v1);
    }
  }
  if (tid < 160) ((float*)hraw[0])[tid] = 0.f;

  float xq0 = outp[0L * HID];
  float xq1 = outp[1L * HID];
  float xq2 = outp[2L * HID];
  float xq3 = outp[3L * HID];
  RNN_BAR();

  #pragma unroll 1
  for (int t4 = 0; t4 < T; t4 += 4) {
    FDOT_STEP(0, xq0)
    FDOT_STEP(1, xq1)
    FDOT_STEP(2, xq2)
    FDOT_STEP(3, xq3)
  }
}

// ===========================================================================
extern "C" void kernel_launch(void* const* d_in, const int* in_sizes, int n_in,
                              void* d_out, int out_size, void* d_ws, size_t ws_size,
                              hipStream_t stream) {
  const float* x   = (const float*)d_in[0];
  const float* Wxh = (const float*)d_in[1];
  const float* Whh = (const float*)d_in[2];
  const float* bh  = (const float*)d_in[3];
  float* out = (float*)d_out;

  const size_t xpt_bytes = (size_t)BATCH * SEQT * HID * sizeof(half_t);  // 64 MB
  if (ws_size >= xpt_bytes) {
    half_t* xpT = (half_t*)d_ws;
    xproj_v3<<<dim3(NG, SEQT / TCH), dim3(512), 0, stream>>>(x, Wxh, bh, xpT);
    rnn_mfma<<<dim3(NG), dim3(256), 0, stream>>>(Whh, xpT, out, SEQT);
  } else if (ws_size >= (size_t)(DIM * HID * sizeof(half_t))) {
    half_t* Wh = (half_t*)d_ws;
    cvt_w_kernel<<<dim3((DIM * HID) / 1024), dim3(256), 0, stream>>>(Wxh, Wh);
    xproj_f16_v2<<<dim3((BATCH * SEQT) / 128), dim3(256), 0, stream>>>(x, Wh, bh, out);
    rnn_fdot<<<dim3(BATCH), dim3(512), 0, stream>>>(Whh, out, SEQT);
  } else {
    xproj_f16_v2<<<dim3((BATCH * SEQT) / 128), dim3(256), 0, stream>>>(
        x, (const half_t*)Wxh, bh, out);  // unreachable in practice
    rnn_fdot<<<dim3(BATCH), dim3(512), 0, stream>>>(Whh, out, SEQT);
  }
}

// Round 11
// 2468.454 us; speedup vs baseline: 12.4485x; 1.0169x over previous
//
#include <hip/hip_runtime.h>

#define BATCH 64
#define SEQT  2048
#define DIM   256   // INPUT_SIZE
#define HID   256   // HIDDEN_SIZE
#define NG    4     // chain groups (blocks for MFMA rnn)
#define GC    16    // chains per group
#define TCH   8     // t-steps per xproj_v3 block
#define HSTR  264   // hlds chain-row stride in f16 (528 B, 16B-aligned)

typedef _Float16 half_t;
typedef _Float16 half2_t __attribute__((ext_vector_type(2)));
typedef _Float16 half4_t __attribute__((ext_vector_type(4)));
typedef _Float16 half8_t __attribute__((ext_vector_type(8)));
typedef float    float4_t __attribute__((ext_vector_type(4)));

__device__ __forceinline__ half8_t cvt8(float4_t a, float4_t b) {
  half8_t r;
  r[0] = (half_t)a[0]; r[1] = (half_t)a[1]; r[2] = (half_t)a[2]; r[3] = (half_t)a[3];
  r[4] = (half_t)b[0]; r[5] = (half_t)b[1]; r[6] = (half_t)b[2]; r[7] = (half_t)b[3];
  return r;
}
#define H2X(v, c) __builtin_shufflevector((v), (v), 2*(c), 2*(c)+1)

template<int CTRL>
__device__ __forceinline__ float dpp_mov(float a) {
  int t = __builtin_amdgcn_mov_dpp(__builtin_bit_cast(int, a), CTRL, 0xF, 0xF, true);
  return __builtin_bit_cast(float, t);
}

#define RNN_BAR() asm volatile("s_waitcnt lgkmcnt(0)\n\ts_barrier" ::: "memory")

// ===========================================================================
// PRIMARY PATH (needs ws >= 64MB for xpT)
// xpT element offset: F(g,t,n,c) = (((g*SEQT+t)*64 + (n>>2))*GC + c)*4 + (n&3)
// -> every wave-level xp load/store is one contiguous 512 B segment.
// ===========================================================================

__global__ __launch_bounds__(512, 1) void xproj_v3(
    const float* __restrict__ x, const float* __restrict__ Wxh,
    const float* __restrict__ bh, half_t* __restrict__ xpT)
{
  const int l = threadIdx.x & 63;
  const int w = threadIdx.x >> 6;    // 0..7
  const int s = l & 15;
  const int q = l >> 4;
  const int g = blockIdx.x;
  const int t0 = blockIdx.y * TCH;
  const long b0 = (long)g * GC;

  half8_t aw[2][8];
  #pragma unroll
  for (int i = 0; i < 2; ++i) {
    const float* wr = Wxh + (long)((w * 2 + i) * 16 + s) * DIM + q * 8;
    #pragma unroll
    for (int kf = 0; kf < 8; ++kf) {
      float4_t v0 = *(const float4_t*)(wr + kf * 32);
      float4_t v1 = *(const float4_t*)(wr + kf * 32 + 4);
      aw[i][kf] = cvt8(v0, v1);
    }
  }
  float4_t bia[2];
  #pragma unroll
  for (int i = 0; i < 2; ++i)
    bia[i] = *(const float4_t*)(bh + (w * 2 + i) * 16 + q * 4);

  #pragma unroll 1
  for (int tt = 0; tt < TCH; ++tt) {
    const int t = t0 + tt;
    half8_t bx[8];
    const float* xr = x + ((b0 + s) * (long)SEQT + t) * DIM + q * 8;
    #pragma unroll
    for (int kf = 0; kf < 8; ++kf) {
      float4_t v0 = *(const float4_t*)(xr + kf * 32);
      float4_t v1 = *(const float4_t*)(xr + kf * 32 + 4);
      bx[kf] = cvt8(v0, v1);
    }
    #pragma unroll
    for (int i = 0; i < 2; ++i) {
      float4_t acc = bia[i];
      #pragma unroll
      for (int kf = 0; kf < 8; ++kf)
        acc = __builtin_amdgcn_mfma_f32_16x16x32_f16(aw[i][kf], bx[kf], acc, 0, 0, 0);
      half4_t h4;
      h4[0] = (half_t)acc[0]; h4[1] = (half_t)acc[1];
      h4[2] = (half_t)acc[2]; h4[3] = (half_t)acc[3];
      long off = (((long)(g * SEQT + t) * 64) + (w * 2 + i) * 4 + q) * (GC * 4) + s * 4;
      *(half4_t*)(xpT + off) = h4;
    }
  }
}

// ---------------------------------------------------------------------------
// rnn_mfma v3: same structure as v2 (coalesced xp/y, 4-slot ring), but the
// MFMA inner loop is restructured for in-order-issue latency hiding:
//   - kf-OUTER rounds (chains advance together, not one chain at a time)
//   - split-K double accumulators: accA (kf 0-3, seeded with xp C-in) and
//     accB (kf 4-7, seeded 0) -> 8 INDEPENDENT dependency streams/wave;
//     each round issues 8 independent MFMAs (~40 cyc) >= accumulate latency,
//     so the wave never stalls on MFMA forwarding.  acc = accA+accB at end.
// ---------------------------------------------------------------------------
#define MFMA16(A, B, C) __builtin_amdgcn_mfma_f32_16x16x32_f16((A), (B), (C), 0, 0, 0)

#define RNN_ROUND(r)                                                           \
    accA0 = MFMA16(aw[0][(r)], bh8[(r)], accA0);                               \
    accA1 = MFMA16(aw[1][(r)], bh8[(r)], accA1);                               \
    accA2 = MFMA16(aw[2][(r)], bh8[(r)], accA2);                               \
    accA3 = MFMA16(aw[3][(r)], bh8[(r)], accA3);                               \
    accB0 = MFMA16(aw[0][(r) + 4], bh8[(r) + 4], accB0);                       \
    accB1 = MFMA16(aw[1][(r) + 4], bh8[(r) + 4], accB1);                       \
    accB2 = MFMA16(aw[2][(r) + 4], bh8[(r) + 4], accB2);                       \
    accB3 = MFMA16(aw[3][(r) + 4], bh8[(r) + 4], accB3);

#define RNN_EPI(i, ACCA, ACCB)                                                 \
  {                                                                            \
    float4_t f = ACCA + ACCB;                                                  \
    half4_t h4;                                                                \
    h4[0] = (half_t)fmaxf(f[0], 0.f); h4[1] = (half_t)fmaxf(f[1], 0.f);        \
    h4[2] = (half_t)fmaxf(f[2], 0.f); h4[3] = (half_t)fmaxf(f[3], 0.f);        \
    *(half4_t*)&hlds[(UU)][s * HSTR + (4 * w + (i)) * 16 + 4 * q] = h4;        \
  }

#define RNN_MSTEP(U, XQ)                                                       \
  {                                                                            \
    const int UU = (U);                                                        \
    const int t = t4 + (U);                                                    \
    half8_t bh8[8];                                                            \
    _Pragma("unroll")                                                          \
    for (int kf = 0; kf < 8; ++kf)                                             \
      bh8[kf] = *(const half8_t*)&hlds[((U) + 3) & 3][s * HSTR + 32 * kf + 8 * q]; \
    /* accA seeded with xp C-in; accB seeded 0 (split-K) */                    \
    float4_t accA0, accA1, accA2, accA3;                                       \
    accA0[0] = (float)XQ[0][0]; accA0[1] = (float)XQ[0][1];                    \
    accA0[2] = (float)XQ[0][2]; accA0[3] = (float)XQ[0][3];                    \
    accA1[0] = (float)XQ[1][0]; accA1[1] = (float)XQ[1][1];                    \
    accA1[2] = (float)XQ[1][2]; accA1[3] = (float)XQ[1][3];                    \
    accA2[0] = (float)XQ[2][0]; accA2[1] = (float)XQ[2][1];                    \
    accA2[2] = (float)XQ[2][2]; accA2[3] = (float)XQ[2][3];                    \
    accA3[0] = (float)XQ[3][0]; accA3[1] = (float)XQ[3][1];                    \
    accA3[2] = (float)XQ[3][2]; accA3[3] = (float)XQ[3][3];                    \
    float4_t accB0 = {0.f, 0.f, 0.f, 0.f}, accB1 = {0.f, 0.f, 0.f, 0.f};       \
    float4_t accB2 = {0.f, 0.f, 0.f, 0.f}, accB3 = {0.f, 0.f, 0.f, 0.f};       \
    /* refill XQ for t+4 (coalesced 512B wave loads, uniform clamped) */       \
    {                                                                          \
      const long tp = (t + 4 < T) ? (t + 4) : (T - 1);                         \
      _Pragma("unroll")                                                        \
      for (int i = 0; i < 4; ++i)                                              \
        XQ[i] = *(const half4_t*)(xpg +                                        \
            (tp * 64 + (4 * w + i) * 4 + q) * (GC * 4) + s * 4);               \
    }                                                                          \
    RNN_ROUND(0) RNN_ROUND(1) RNN_ROUND(2) RNN_ROUND(3)                        \
    RNN_EPI(0, accA0, accB0) RNN_EPI(1, accA1, accB1)                          \
    RNN_EPI(2, accA2, accB2) RNN_EPI(3, accA3, accB3)                          \
    RNN_BAR();                                                                 \
  }

#define RNN_YSTORE(tt)                                                         \
  {                                                                            \
    half8_t v0 = *(const half8_t*)&hlds[(tt)][c * HSTR + sub * 16];            \
    half8_t v1 = *(const half8_t*)&hlds[(tt)][c * HSTR + sub * 16 + 8];        \
    float* op = outg + (long)c * SEQT * HID + (long)(t4 + (tt)) * HID + sub * 16; \
    float4_t o;                                                                \
    o[0] = (float)v0[0]; o[1] = (float)v0[1]; o[2] = (float)v0[2]; o[3] = (float)v0[3]; \
    *(float4_t*)op = o;                                                        \
    o[0] = (float)v0[4]; o[1] = (float)v0[5]; o[2] = (float)v0[6]; o[3] = (float)v0[7]; \
    *(float4_t*)(op + 4) = o;                                                  \
    o[0] = (float)v1[0]; o[1] = (float)v1[1]; o[2] = (float)v1[2]; o[3] = (float)v1[3]; \
    *(float4_t*)(op + 8) = o;                                                  \
    o[0] = (float)v1[4]; o[1] = (float)v1[5]; o[2] = (float)v1[6]; o[3] = (float)v1[7]; \
    *(float4_t*)(op + 12) = o;                                                 \
  }

__global__ __launch_bounds__(256, 1) void rnn_mfma(
    const float* __restrict__ Whh, const half_t* __restrict__ xpT,
    float* __restrict__ out, int T)
{
  __shared__ alignas(16) half_t hlds[4][GC * HSTR];

  const int l = threadIdx.x & 63;
  const int w = threadIdx.x >> 6;   // 0..3
  const int s = l & 15;
  const int q = l >> 4;
  const int g = blockIdx.x;
  const int c   = threadIdx.x >> 4;  // store-phase chain (0..15)
  const int sub = threadIdx.x & 15;  // store-phase n-sixteenth

  const half_t* xpg = xpT + (long)g * SEQT * (GC * HID);
  float* outg = out + (long)g * GC * SEQT * HID;

  // A-frags: W_hh[16nt+s][32kf+8q .. +8], nt = 4w..4w+3 (128 VGPR)
  half8_t aw[4][8];
  #pragma unroll
  for (int i = 0; i < 4; ++i) {
    const float* wr = Whh + (long)((4 * w + i) * 16 + s) * HID + q * 8;
    #pragma unroll
    for (int kf = 0; kf < 8; ++kf) {
      float4_t v0 = *(const float4_t*)(wr + kf * 32);
      float4_t v1 = *(const float4_t*)(wr + kf * 32 + 4);
      aw[i][kf] = cvt8(v0, v1);
    }
  }

  // zero the ring (slot 3 = h_{-1} = 0 is what matters)
  {
    half8_t z8 = {0, 0, 0, 0, 0, 0, 0, 0};
    for (int i = threadIdx.x; i < 4 * GC * HSTR / 8; i += 256)
      ((half8_t*)hlds)[i] = z8;
  }

  // 4-deep xp prefetch: xq{0..3} hold xp for t = 0..3
  half4_t xq0[4], xq1[4], xq2[4], xq3[4];
  #pragma unroll
  for (int i = 0; i < 4; ++i) {
    const long nb = (4 * w + i) * 4 + q;
    xq0[i] = *(const half4_t*)(xpg + (0L * 64 + nb) * (GC * 4) + s * 4);
    xq1[i] = *(const half4_t*)(xpg + (1L * 64 + nb) * (GC * 4) + s * 4);
    xq2[i] = *(const half4_t*)(xpg + (2L * 64 + nb) * (GC * 4) + s * 4);
    xq3[i] = *(const half4_t*)(xpg + (3L * 64 + nb) * (GC * 4) + s * 4);
  }
  RNN_BAR();

  #pragma unroll 1
  for (int t4 = 0; t4 < T; t4 += 4) {
    RNN_MSTEP(0, xq0)
    RNN_MSTEP(1, xq1)
    RNN_MSTEP(2, xq2)
    RNN_MSTEP(3, xq3)
    RNN_YSTORE(0) RNN_YSTORE(1) RNN_YSTORE(2) RNN_YSTORE(3)
    RNN_BAR();   // protect ring slots from next iteration's overwrites
  }
}

// ===========================================================================
// FALLBACK PATH (round-6 rnn @851us + B-stationary xproj) if ws < 64MB
// ===========================================================================

__global__ __launch_bounds__(256) void cvt_w_kernel(
    const float* __restrict__ W, half_t* __restrict__ Wh)
{
  const int i = (blockIdx.x * 256 + threadIdx.x) * 4;
  float4_t v = *(const float4_t*)(W + i);
  half4_t o; o[0]=(half_t)v[0]; o[1]=(half_t)v[1]; o[2]=(half_t)v[2]; o[3]=(half_t)v[3];
  *(half4_t*)(Wh + i) = o;
}

__global__ __launch_bounds__(256) void xproj_f16_v2(
    const float* __restrict__ x, const half_t* __restrict__ Wh,
    const float* __restrict__ bh, float* __restrict__ out)
{
  const int lane = threadIdx.x & 63;
  const int wave = threadIdx.x >> 6;
  const int r16  = lane & 15;
  const int kg   = lane >> 4;
  const long m0  = (long)blockIdx.x * 128;

  half8_t bfr[4][8];
  float bb[4];
  #pragma unroll
  for (int qq = 0; qq < 4; ++qq) {
    const int nt = wave * 4 + qq;
    const half_t* wr = Wh + (nt * 16 + r16) * (long)DIM + kg * 8;
    #pragma unroll
    for (int kf = 0; kf < 8; ++kf)
      bfr[qq][kf] = *(const half8_t*)(wr + kf * 32);
    bb[qq] = bh[nt * 16 + r16];
  }
  #pragma unroll 1
  for (int mi = 0; mi < 8; ++mi) {
    const long mrow = m0 + mi * 16;
    half8_t a[8];
    const float* xr = x + (mrow + r16) * (long)DIM + kg * 8;
    #pragma unroll
    for (int kf = 0; kf < 8; ++kf) {
      float4_t x0 = *(const float4_t*)(xr + kf * 32);
      float4_t x1 = *(const float4_t*)(xr + kf * 32 + 4);
      a[kf] = cvt8(x0, x1);
    }
    #pragma unroll
    for (int qq = 0; qq < 4; ++qq) {
      float4_t acc = {bb[qq], bb[qq], bb[qq], bb[qq]};
      #pragma unroll
      for (int kf = 0; kf < 8; ++kf)
        acc = __builtin_amdgcn_mfma_f32_16x16x32_f16(a[kf], bfr[qq][kf], acc, 0, 0, 0);
      float* op = out + (mrow + kg * 4) * (long)HID + (wave * 4 + qq) * 16 + r16;
      #pragma unroll
      for (int r = 0; r < 4; ++r) op[(long)r * HID] = acc[r];
    }
  }
}

#define FDOT_STEP(U, XQ)                                                       \
  {                                                                            \
    const int t = t4 + (U);                                                    \
    const int tp = (t + 4 < T) ? (t + 4) : (T - 1);                            \
    float xnew = outp[(long)tp * HID];                                         \
    half8_t hv[4];                                                             \
    _Pragma("unroll")                                                          \
    for (int ss = 0; ss < 4; ++ss)                                             \
      hv[ss] = *(const half8_t*)(hraw[(U) & 1] + rb + 16 * ss);                \
    float a0 = 0.f, a1 = 0.f, a2 = 0.f, a3 = 0.f;                              \
    _Pragma("unroll")                                                          \
    for (int ss = 0; ss < 4; ++ss) {                                           \
      a0 = __builtin_amdgcn_fdot2(H2X(w8[0][ss], 0), H2X(hv[ss], 0), a0, false); \
      a0 = __builtin_amdgcn_fdot2(H2X(w8[0][ss], 1), H2X(hv[ss], 1), a0, false); \
      a0 = __builtin_amdgcn_fdot2(H2X(w8[0][ss], 2), H2X(hv[ss], 2), a0, false); \
      a0 = __builtin_amdgcn_fdot2(H2X(w8[0][ss], 3), H2X(hv[ss], 3), a0, false); \
      a1 = __builtin_amdgcn_fdot2(H2X(w8[1][ss], 0), H2X(hv[ss], 0), a1, false); \
      a1 = __builtin_amdgcn_fdot2(H2X(w8[1][ss], 1), H2X(hv[ss], 1), a1, false); \
      a1 = __builtin_amdgcn_fdot2(H2X(w8[1][ss], 2), H2X(hv[ss], 2), a1, false); \
      a1 = __builtin_amdgcn_fdot2(H2X(w8[1][ss], 3), H2X(hv[ss], 3), a1, false); \
      a2 = __builtin_amdgcn_fdot2(H2X(w8[2][ss], 0), H2X(hv[ss], 0), a2, false); \
      a2 = __builtin_amdgcn_fdot2(H2X(w8[2][ss], 1), H2X(hv[ss], 1), a2, false); \
      a2 = __builtin_amdgcn_fdot2(H2X(w8[2][ss], 2), H2X(hv[ss], 2), a2, false); \
      a2 = __builtin_amdgcn_fdot2(H2X(w8[2][ss], 3), H2X(hv[ss], 3), a2, false); \
      a3 = __builtin_amdgcn_fdot2(H2X(w8[3][ss], 0), H2X(hv[ss], 0), a3, false); \
      a3 = __builtin_amdgcn_fdot2(H2X(w8[3][ss], 1), H2X(hv[ss], 1), a3, false); \
      a3 = __builtin_amdgcn_fdot2(H2X(w8[3][ss], 2), H2X(hv[ss], 2), a3, false); \
      a3 = __builtin_amdgcn_fdot2(H2X(w8[3][ss], 3), H2X(hv[ss], 3), a3, false); \
    }                                                                          \
    float r0 = kA ? a0 : a2;                                                   \
    float r1 = kA ? a1 : a3;                                                   \
    float b0 = (kA ? a2 : a0) + dpp_mov<0x141>(r0);                            \
    float b1 = (kA ? a3 : a1) + dpp_mov<0x141>(r1);                            \
    float rB = kB ? b0 : b1;                                                   \
    float cX = (kB ? b1 : b0) + dpp_mov<0x4E>(rB);                             \
    float fin = cX + dpp_mov<0xB1>(cX);                                        \
    float y = fmaxf(fin + (XQ), 0.f);                                          \
    outp[(long)t * HID] = y;                                                   \
    *(half_t*)(hraw[((U) & 1) ^ 1] + hwb) = (half_t)y;                         \
    XQ = xnew;                                                                 \
    RNN_BAR();                                                                 \
  }

__global__ __launch_bounds__(512, 1) void rnn_fdot(
    const float* __restrict__ Whh, float* __restrict__ out, int T)
{
  __shared__ alignas(128) unsigned char hraw[2][8 * 80];

  const int tid = threadIdx.x;
  const int l   = tid & 63;
  const int w   = tid >> 6;
  const int g   = l & 7;
  const int j0  = w * 32 + (l >> 3) * 4;
  const int rb  = g * 80;
  const int jown = j0 + ((l >> 1) & 3);
  const int hwb = ((jown >> 5) * 80 + (jown & 31) * 2);
  const bool kA = (l & 4) != 0;
  const bool kB = (l & 2) != 0;
  float* outp = out + (long)blockIdx.x * SEQT * HID + jown;

  half8_t w8[4][4];
  #pragma unroll
  for (int i = 0; i < 4; ++i) {
    const float* wr = Whh + (long)(j0 + i) * HID + g * 32;
    #pragma unroll
    for (int ss = 0; ss < 4; ++ss) {
      float4_t v0 = *(const float4_t*)(wr + ss * 8);
      float4_t v1 = *(const float4_t*)(wr + ss * 8 + 4);
      w8[i][ss] = cvt8(v0, v1);
    }
  }
  if (tid < 160) ((float*)hraw[0])[tid] = 0.f;

  float xq0 = outp[0L * HID];
  float xq1 = outp[1L * HID];
  float xq2 = outp[2L * HID];
  float xq3 = outp[3L * HID];
  RNN_BAR();

  #pragma unroll 1
  for (int t4 = 0; t4 < T; t4 += 4) {
    FDOT_STEP(0, xq0)
    FDOT_STEP(1, xq1)
    FDOT_STEP(2, xq2)
    FDOT_STEP(3, xq3)
  }
}

// ===========================================================================
extern "C" void kernel_launch(void* const* d_in, const int* in_sizes, int n_in,
                              void* d_out, int out_size, void* d_ws, size_t ws_size,
                              hipStream_t stream) {
  const float* x   = (const float*)d_in[0];
  const float* Wxh = (const float*)d_in[1];
  const float* Whh = (const float*)d_in[2];
  const float* bh  = (const float*)d_in[3];
  float* out = (float*)d_out;

  const size_t xpt_bytes = (size_t)BATCH * SEQT * HID * sizeof(half_t);  // 64 MB
  if (ws_size >= xpt_bytes) {
    half_t* xpT = (half_t*)d_ws;
    xproj_v3<<<dim3(NG, SEQT / TCH), dim3(512), 0, stream>>>(x, Wxh, bh, xpT);
    rnn_mfma<<<dim3(NG), dim3(256), 0, stream>>>(Whh, xpT, out, SEQT);
  } else if (ws_size >= (size_t)(DIM * HID * sizeof(half_t))) {
    half_t* Wh = (half_t*)d_ws;
    cvt_w_kernel<<<dim3((DIM * HID) / 1024), dim3(256), 0, stream>>>(Wxh, Wh);
    xproj_f16_v2<<<dim3((BATCH * SEQT) / 128), dim3(256), 0, stream>>>(x, Wh, bh, out);
    rnn_fdot<<<dim3(BATCH), dim3(512), 0, stream>>>(Whh, out, SEQT);
  } else {
    xproj_f16_v2<<<dim3((BATCH * SEQT) / 128), dim3(256), 0, stream>>>(
        x, (const half_t*)Wxh, bh, out);  // unreachable in practice
    rnn_fdot<<<dim3(BATCH), dim3(512), 0, stream>>>(Whh, out, SEQT);
  }
}

// Round 12
// 1019.414 us; speedup vs baseline: 30.1435x; 2.4214x over previous
//
#include <hip/hip_runtime.h>

#define BATCH 64
#define SEQT  2048
#define DIM   256   // INPUT_SIZE
#define HID   256   // HIDDEN_SIZE

typedef _Float16 half_t;
typedef _Float16 half2_t __attribute__((ext_vector_type(2)));
typedef _Float16 half4_t __attribute__((ext_vector_type(4)));
typedef _Float16 half8_t __attribute__((ext_vector_type(8)));
typedef float    float4_t __attribute__((ext_vector_type(4)));

__device__ __forceinline__ half8_t cvt8(float4_t a, float4_t b) {
  half8_t r;
  r[0] = (half_t)a[0]; r[1] = (half_t)a[1]; r[2] = (half_t)a[2]; r[3] = (half_t)a[3];
  r[4] = (half_t)b[0]; r[5] = (half_t)b[1]; r[6] = (half_t)b[2]; r[7] = (half_t)b[3];
  return r;
}
// extract half2 #c from a half8 (c MUST be a parse-time literal)
#define H2X(v, c) __builtin_shufflevector((v), (v), 2*(c), 2*(c)+1)

// packed f16 FMA: d = a*b + c elementwise -> v_pk_fma_f16 (VOP3P, full rate)
__device__ __forceinline__ half2_t pkfma(half2_t a, half2_t b, half2_t c) {
#if __has_builtin(__builtin_elementwise_fma)
  return __builtin_elementwise_fma(a, b, c);
#else
  return a * b + c;
#endif
}

// DPP lane-move (pure VALU).  0xB1 = quad_perm lane^1; 0x4E = quad_perm
// lane^2; 0x141 = row_half_mirror (XOR7 within 8).
template<int CTRL>
__device__ __forceinline__ float dpp_mov(float a) {
  int t = __builtin_amdgcn_mov_dpp(__builtin_bit_cast(int, a), CTRL, 0xF, 0xF, true);
  return __builtin_bit_cast(float, t);
}

#define RNN_BAR() asm volatile("s_waitcnt lgkmcnt(0)\n\ts_barrier" ::: "memory")

// ---------------------------------------------------------------------------
// Kernel 0: convert W_xh fp32 -> f16 into d_ws (one-time, trivial).
// ---------------------------------------------------------------------------
__global__ __launch_bounds__(256) void cvt_w_kernel(
    const float* __restrict__ W, half_t* __restrict__ Wh)
{
  const int i = (blockIdx.x * 256 + threadIdx.x) * 4;
  float4_t v = *(const float4_t*)(W + i);
  half4_t o; o[0]=(half_t)v[0]; o[1]=(half_t)v[1]; o[2]=(half_t)v[2]; o[3]=(half_t)v[3];
  *(half4_t*)(Wh + i) = o;
}

// ---------------------------------------------------------------------------
// Kernel 1 (B-stationary): P[m,n] = sum_k x[m,k]*Wxh[n,k] + bh[n] -> out.
// 1024 blocks x 128 rows; wave owns 4 n-tiles (B-frags loaded once).
// ---------------------------------------------------------------------------
__global__ __launch_bounds__(256) void xproj_f16_v2(
    const float* __restrict__ x, const half_t* __restrict__ Wh,
    const float* __restrict__ bh, float* __restrict__ out)
{
  const int lane = threadIdx.x & 63;
  const int wave = threadIdx.x >> 6;
  const int r16  = lane & 15;
  const int kg   = lane >> 4;
  const long m0  = (long)blockIdx.x * 128;

  half8_t bfr[4][8];
  float bb[4];
  #pragma unroll
  for (int qq = 0; qq < 4; ++qq) {
    const int nt = wave * 4 + qq;
    const half_t* wr = Wh + (nt * 16 + r16) * (long)DIM + kg * 8;
    #pragma unroll
    for (int kf = 0; kf < 8; ++kf)
      bfr[qq][kf] = *(const half8_t*)(wr + kf * 32);
    bb[qq] = bh[nt * 16 + r16];
  }
  #pragma unroll 1
  for (int mi = 0; mi < 8; ++mi) {
    const long mrow = m0 + mi * 16;
    half8_t a[8];
    const float* xr = x + (mrow + r16) * (long)DIM + kg * 8;
    #pragma unroll
    for (int kf = 0; kf < 8; ++kf) {
      float4_t x0 = *(const float4_t*)(xr + kf * 32);
      float4_t x1 = *(const float4_t*)(xr + kf * 32 + 4);
      a[kf] = cvt8(x0, x1);
    }
    #pragma unroll
    for (int qq = 0; qq < 4; ++qq) {
      float4_t acc = {bb[qq], bb[qq], bb[qq], bb[qq]};
      #pragma unroll
      for (int kf = 0; kf < 8; ++kf)
        acc = __builtin_amdgcn_mfma_f32_16x16x32_f16(a[kf], bfr[qq][kf], acc, 0, 0, 0);
      float* op = out + (mrow + kg * 4) * (long)HID + (wave * 4 + qq) * 16 + r16;
      #pragma unroll
      for (int r = 0; r < 4; ++r) op[(long)r * HID] = acc[r];
    }
  }
}

// fp32-weight fallback (ws too small for Wh)
__global__ __launch_bounds__(256) void xproj_kernel(
    const float* __restrict__ x, const float* __restrict__ Wxh,
    const float* __restrict__ bh, float* __restrict__ out)
{
  const int lane = threadIdx.x & 63;
  const int wave = threadIdx.x >> 6;
  const int r16  = lane & 15;
  const int kg   = lane >> 4;
  const long m0  = (long)blockIdx.x * 64 + wave * 16;

  half8_t a[8];
  const float* xr = x + (m0 + r16) * (long)DIM + kg * 8;
  #pragma unroll
  for (int kf = 0; kf < 8; ++kf) {
    float4_t x0 = *(const float4_t*)(xr + kf * 32);
    float4_t x1 = *(const float4_t*)(xr + kf * 32 + 4);
    a[kf] = cvt8(x0, x1);
  }
  for (int nt = 0; nt < 16; ++nt) {
    const float* wr = Wxh + (nt * 16 + r16) * (long)DIM + kg * 8;
    float bb = bh[nt * 16 + r16];
    float4_t acc = {bb, bb, bb, bb};
    #pragma unroll
    for (int kf = 0; kf < 8; ++kf) {
      float4_t w0 = *(const float4_t*)(wr + kf * 32);
      float4_t w1 = *(const float4_t*)(wr + kf * 32 + 4);
      acc = __builtin_amdgcn_mfma_f32_16x16x32_f16(a[kf], cvt8(w0, w1), acc, 0, 0, 0);
    }
    float* op = out + (m0 + kg * 4) * (long)HID + nt * 16 + r16;
    #pragma unroll
    for (int r = 0; r < 4; ++r) op[(long)r * HID] = acc[r];
  }
}

// ---------------------------------------------------------------------------
// Kernel 2 (v8 = v6 structure + v_pk_fma_f16 dots):
// h_t = relu(xp_t + W_hh h_{t-1}).  One block per chain, 512 thr = 8 waves.
// lane l of wave w: g = l&7 (32-col K-chunk), quad q = l>>3.
// Thread: 4 partial outputs (rows 32w+4q..+4) over chunk g = 64 v_pk_fma_f16
// into f16-pair accumulators (full-rate 2cyc vs fdot2's 4cyc half-rate),
// finalized to f32 (2 cvt + 1 add each).  Precision: 16 products per f16
// half-slot -> ~1e-3 extra error, well under threshold.
// Reduce-scatter (unchanged from v6, verified): DPP {XOR7 keep bit1, XOR2
// keep bit0, XOR1 all-reduce} -> lanes {l,l^1} own output j = 32w + 4*(l>>3)
// + ((l>>1)&3); dup stores benign.  Branch-free epilogue; xp prefetch 4 deep
// at uniform clamped addresses; lgkmcnt-only barrier keeps globals in flight.
// LDS h: chunk g at byte 80g -> conflict-free b128 reads (banks 20g mod 32).
// ---------------------------------------------------------------------------
#define RNN_STEP(U, XQ)                                                        \
  {                                                                            \
    const int t = t4 + (U);                                                    \
    const int tp = (t + 4 < T) ? (t + 4) : (T - 1);                            \
    float xnew = outp[(long)tp * HID];                                         \
    half8_t hv[4];                                                             \
    _Pragma("unroll")                                                          \
    for (int s = 0; s < 4; ++s)                                                \
      hv[s] = *(const half8_t*)(hraw[(U) & 1] + rb + 16 * s);                  \
    half2_t p0 = {0, 0}, p1 = {0, 0}, p2 = {0, 0}, p3 = {0, 0};                \
    _Pragma("unroll")                                                          \
    for (int s = 0; s < 4; ++s) {                                              \
      p0 = pkfma(H2X(w8[0][s], 0), H2X(hv[s], 0), p0);                         \
      p0 = pkfma(H2X(w8[0][s], 1), H2X(hv[s], 1), p0);                         \
      p0 = pkfma(H2X(w8[0][s], 2), H2X(hv[s], 2), p0);                         \
      p0 = pkfma(H2X(w8[0][s], 3), H2X(hv[s], 3), p0);                         \
      p1 = pkfma(H2X(w8[1][s], 0), H2X(hv[s], 0), p1);                         \
      p1 = pkfma(H2X(w8[1][s], 1), H2X(hv[s], 1), p1);                         \
      p1 = pkfma(H2X(w8[1][s], 2), H2X(hv[s], 2), p1);                         \
      p1 = pkfma(H2X(w8[1][s], 3), H2X(hv[s], 3), p1);                         \
      p2 = pkfma(H2X(w8[2][s], 0), H2X(hv[s], 0), p2);                         \
      p2 = pkfma(H2X(w8[2][s], 1), H2X(hv[s], 1), p2);                         \
      p2 = pkfma(H2X(w8[2][s], 2), H2X(hv[s], 2), p2);                         \
      p2 = pkfma(H2X(w8[2][s], 3), H2X(hv[s], 3), p2);                         \
      p3 = pkfma(H2X(w8[3][s], 0), H2X(hv[s], 0), p3);                         \
      p3 = pkfma(H2X(w8[3][s], 1), H2X(hv[s], 1), p3);                         \
      p3 = pkfma(H2X(w8[3][s], 2), H2X(hv[s], 2), p3);                         \
      p3 = pkfma(H2X(w8[3][s], 3), H2X(hv[s], 3), p3);                         \
    }                                                                          \
    float a0 = (float)p0[0] + (float)p0[1];                                    \
    float a1 = (float)p1[0] + (float)p1[1];                                    \
    float a2 = (float)p2[0] + (float)p2[1];                                    \
    float a3 = (float)p3[0] + (float)p3[1];                                    \
    /* reduce-scatter: lanes {l,l^1} end with full sum of index (l>>1)&3 */    \
    float r0 = kA ? a0 : a2;   /* stage A: XOR7, keep bit1==kA */              \
    float r1 = kA ? a1 : a3;                                                   \
    float b0 = (kA ? a2 : a0) + dpp_mov<0x141>(r0);                            \
    float b1 = (kA ? a3 : a1) + dpp_mov<0x141>(r1);                            \
    float rB = kB ? b0 : b1;   /* stage B: XOR2, keep bit0==kB */              \
    float c  = (kB ? b1 : b0) + dpp_mov<0x4E>(rB);                             \
    float fin = c + dpp_mov<0xB1>(c);   /* stage C: XOR1 all-reduce */         \
    float y = fmaxf(fin + (XQ), 0.f);                                          \
    outp[(long)t * HID] = y;                                                   \
    *(half_t*)(hraw[((U) & 1) ^ 1] + hwb) = (half_t)y;                         \
    XQ = xnew;                                                                 \
    RNN_BAR();                                                                 \
  }

__global__ __launch_bounds__(512, 1) void rnn_kernel(
    const float* __restrict__ Whh, float* __restrict__ out, int T)
{
  // 8 chunks x (64B data + 16B pad), double buffered
  __shared__ alignas(128) unsigned char hraw[2][8 * 80];

  const int tid = threadIdx.x;
  const int l   = tid & 63;
  const int w   = tid >> 6;                // wave 0..7
  const int g   = l & 7;                   // K-chunk: columns [32g, 32g+32)
  const int j0  = w * 32 + (l >> 3) * 4;   // partial rows [j0, j0+4)
  const int rb  = g * 80;                  // LDS read base (bytes)
  const int jown = j0 + ((l >> 1) & 3);    // output row OWNED post-reduce
  const int hwb = ((jown >> 5) * 80 + (jown & 31) * 2);  // LDS write byte
  const bool kA = (l & 4) != 0;
  const bool kB = (l & 2) != 0;
  float* outp = out + (long)blockIdx.x * SEQT * HID + jown;

  // W_hh[j0+i][32g + 8s .. +8] -> w8[i][s]  (64 VGPRs, static indexing)
  half8_t w8[4][4];
  #pragma unroll
  for (int i = 0; i < 4; ++i) {
    const float* wr = Whh + (long)(j0 + i) * HID + g * 32;
    #pragma unroll
    for (int s = 0; s < 4; ++s) {
      float4_t v0 = *(const float4_t*)(wr + s * 8);
      float4_t v1 = *(const float4_t*)(wr + s * 8 + 4);
      w8[i][s] = cvt8(v0, v1);
    }
  }

  // h_0 = 0 (covers data+pads of buffer 0)
  if (tid < 160) ((float*)hraw[0])[tid] = 0.f;

  // 4-deep xp prefetch (named registers -> static indexing), all lanes
  float xq0 = outp[0L * HID];
  float xq1 = outp[1L * HID];
  float xq2 = outp[2L * HID];
  float xq3 = outp[3L * HID];
  RNN_BAR();

  #pragma unroll 1
  for (int t4 = 0; t4 < T; t4 += 4) {
    RNN_STEP(0, xq0)
    RNN_STEP(1, xq1)
    RNN_STEP(2, xq2)
    RNN_STEP(3, xq3)
  }
}

extern "C" void kernel_launch(void* const* d_in, const int* in_sizes, int n_in,
                              void* d_out, int out_size, void* d_ws, size_t ws_size,
                              hipStream_t stream) {
  const float* x   = (const float*)d_in[0];
  const float* Wxh = (const float*)d_in[1];
  const float* Whh = (const float*)d_in[2];
  const float* bh  = (const float*)d_in[3];
  float* out = (float*)d_out;

  if (ws_size >= (size_t)(DIM * HID * sizeof(half_t))) {
    half_t* Wh = (half_t*)d_ws;
    cvt_w_kernel<<<dim3((DIM * HID) / 1024), dim3(256), 0, stream>>>(Wxh, Wh);
    xproj_f16_v2<<<dim3((BATCH * SEQT) / 128), dim3(256), 0, stream>>>(x, Wh, bh, out);
  } else {
    xproj_kernel<<<dim3((BATCH * SEQT) / 64), dim3(256), 0, stream>>>(x, Wxh, bh, out);
  }
  rnn_kernel<<<dim3(BATCH), dim3(512), 0, stream>>>(Whh, out, SEQT);
}

// Round 13
// 940.660 us; speedup vs baseline: 32.6671x; 1.0837x over previous
//
#include <hip/hip_runtime.h>

#define BATCH 64
#define SEQT  2048
#define DIM   256   // INPUT_SIZE
#define HID   256   // HIDDEN_SIZE

typedef _Float16 half_t;
typedef _Float16 half2_t __attribute__((ext_vector_type(2)));
typedef _Float16 half4_t __attribute__((ext_vector_type(4)));
typedef _Float16 half8_t __attribute__((ext_vector_type(8)));
typedef float    float4_t __attribute__((ext_vector_type(4)));

__device__ __forceinline__ half8_t cvt8(float4_t a, float4_t b) {
  half8_t r;
  r[0] = (half_t)a[0]; r[1] = (half_t)a[1]; r[2] = (half_t)a[2]; r[3] = (half_t)a[3];
  r[4] = (half_t)b[0]; r[5] = (half_t)b[1]; r[6] = (half_t)b[2]; r[7] = (half_t)b[3];
  return r;
}
// extract half2 #c from a half8 (c MUST be a parse-time literal)
#define H2X(v, c) __builtin_shufflevector((v), (v), 2*(c), 2*(c)+1)

// DPP lane-move (pure VALU).  0xB1 = quad_perm lane^1; 0x4E = quad_perm
// lane^2; 0x141 = row_half_mirror (XOR7 within 8).
template<int CTRL>
__device__ __forceinline__ float dpp_mov(float a) {
  int t = __builtin_amdgcn_mov_dpp(__builtin_bit_cast(int, a), CTRL, 0xF, 0xF, true);
  return __builtin_bit_cast(float, t);
}

#define RNN_BAR() asm volatile("s_waitcnt lgkmcnt(0)\n\ts_barrier" ::: "memory")

// ---------------------------------------------------------------------------
// Kernel 0: convert W_xh fp32 -> f16 into d_ws (one-time, trivial).
// ---------------------------------------------------------------------------
__global__ __launch_bounds__(256) void cvt_w_kernel(
    const float* __restrict__ W, half_t* __restrict__ Wh)
{
  const int i = (blockIdx.x * 256 + threadIdx.x) * 4;
  float4_t v = *(const float4_t*)(W + i);
  half4_t o; o[0]=(half_t)v[0]; o[1]=(half_t)v[1]; o[2]=(half_t)v[2]; o[3]=(half_t)v[3];
  *(half4_t*)(Wh + i) = o;
}

// ---------------------------------------------------------------------------
// Kernel 1 (B-stationary): P[m,n] = sum_k x[m,k]*Wxh[n,k] + bh[n] -> out.
// 1024 blocks x 128 rows; wave owns 4 n-tiles (B-frags loaded once, 128 VGPR),
// 8 M-tiles stream through.  (measured ~60-90us incl. cvt in rounds 8/12)
// ---------------------------------------------------------------------------
__global__ __launch_bounds__(256) void xproj_f16_v2(
    const float* __restrict__ x, const half_t* __restrict__ Wh,
    const float* __restrict__ bh, float* __restrict__ out)
{
  const int lane = threadIdx.x & 63;
  const int wave = threadIdx.x >> 6;
  const int r16  = lane & 15;
  const int kg   = lane >> 4;
  const long m0  = (long)blockIdx.x * 128;

  half8_t bfr[4][8];
  float bb[4];
  #pragma unroll
  for (int qq = 0; qq < 4; ++qq) {
    const int nt = wave * 4 + qq;
    const half_t* wr = Wh + (nt * 16 + r16) * (long)DIM + kg * 8;
    #pragma unroll
    for (int kf = 0; kf < 8; ++kf)
      bfr[qq][kf] = *(const half8_t*)(wr + kf * 32);
    bb[qq] = bh[nt * 16 + r16];
  }
  #pragma unroll 1
  for (int mi = 0; mi < 8; ++mi) {
    const long mrow = m0 + mi * 16;
    half8_t a[8];
    const float* xr = x + (mrow + r16) * (long)DIM + kg * 8;
    #pragma unroll
    for (int kf = 0; kf < 8; ++kf) {
      float4_t x0 = *(const float4_t*)(xr + kf * 32);
      float4_t x1 = *(const float4_t*)(xr + kf * 32 + 4);
      a[kf] = cvt8(x0, x1);
    }
    #pragma unroll
    for (int qq = 0; qq < 4; ++qq) {
      float4_t acc = {bb[qq], bb[qq], bb[qq], bb[qq]};
      #pragma unroll
      for (int kf = 0; kf < 8; ++kf)
        acc = __builtin_amdgcn_mfma_f32_16x16x32_f16(a[kf], bfr[qq][kf], acc, 0, 0, 0);
      float* op = out + (mrow + kg * 4) * (long)HID + (wave * 4 + qq) * 16 + r16;
      #pragma unroll
      for (int r = 0; r < 4; ++r) op[(long)r * HID] = acc[r];
    }
  }
}

// fp32-weight fallback (ws too small for Wh)
__global__ __launch_bounds__(256) void xproj_kernel(
    const float* __restrict__ x, const float* __restrict__ Wxh,
    const float* __restrict__ bh, float* __restrict__ out)
{
  const int lane = threadIdx.x & 63;
  const int wave = threadIdx.x >> 6;
  const int r16  = lane & 15;
  const int kg   = lane >> 4;
  const long m0  = (long)blockIdx.x * 64 + wave * 16;

  half8_t a[8];
  const float* xr = x + (m0 + r16) * (long)DIM + kg * 8;
  #pragma unroll
  for (int kf = 0; kf < 8; ++kf) {
    float4_t x0 = *(const float4_t*)(xr + kf * 32);
    float4_t x1 = *(const float4_t*)(xr + kf * 32 + 4);
    a[kf] = cvt8(x0, x1);
  }
  for (int nt = 0; nt < 16; ++nt) {
    const float* wr = Wxh + (nt * 16 + r16) * (long)DIM + kg * 8;
    float bb = bh[nt * 16 + r16];
    float4_t acc = {bb, bb, bb, bb};
    #pragma unroll
    for (int kf = 0; kf < 8; ++kf) {
      float4_t w0 = *(const float4_t*)(wr + kf * 32);
      float4_t w1 = *(const float4_t*)(wr + kf * 32 + 4);
      acc = __builtin_amdgcn_mfma_f32_16x16x32_f16(a[kf], cvt8(w0, w1), acc, 0, 0, 0);
    }
    float* op = out + (m0 + kg * 4) * (long)HID + nt * 16 + r16;
    #pragma unroll
    for (int r = 0; r < 4; ++r) op[(long)r * HID] = acc[r];
  }
}

// ---------------------------------------------------------------------------
// Kernel 2 (v6, byte-exact round-6 best @851us): h_t = relu(xp_t + W_hh h_{t-1}).
// One block per chain, 512 threads = 8 waves = 2 waves/SIMD.
// lane l of wave w: g = l&7 (32-col K-chunk), quad q = l>>3.
// Thread: 4 partial outputs (rows 32w+4q .. +4) over chunk g = 64 fdot2.
// Reduce-scatter with DPP masks {XOR7, XOR2, XOR1}:
//   A: XOR7, keep index bit1; B: XOR2, keep bit0; C: XOR1, all-reduce
// -> lanes {l, l^1} BOTH own output j = 32w + 4*(l>>3) + ((l>>1)&3) (dup
// stores benign).  Branch-free epilogue; xp prefetch 4 deep at uniform
// clamped addresses -> deterministic counted vmcnt; lgkmcnt-only barrier
// keeps globals in flight.  LDS h: chunk g at byte 80g -> conflict-free.
// ---------------------------------------------------------------------------
#define RNN_STEP(U, XQ)                                                        \
  {                                                                            \
    const int t = t4 + (U);                                                    \
    const int tp = (t + 4 < T) ? (t + 4) : (T - 1);                            \
    float xnew = outp[(long)tp * HID];                                         \
    half8_t hv[4];                                                             \
    _Pragma("unroll")                                                          \
    for (int s = 0; s < 4; ++s)                                                \
      hv[s] = *(const half8_t*)(hraw[(U) & 1] + rb + 16 * s);                  \
    float a0 = 0.f, a1 = 0.f, a2 = 0.f, a3 = 0.f;                              \
    _Pragma("unroll")                                                          \
    for (int s = 0; s < 4; ++s) {                                              \
      a0 = __builtin_amdgcn_fdot2(H2X(w8[0][s], 0), H2X(hv[s], 0), a0, false); \
      a0 = __builtin_amdgcn_fdot2(H2X(w8[0][s], 1), H2X(hv[s], 1), a0, false); \
      a0 = __builtin_amdgcn_fdot2(H2X(w8[0][s], 2), H2X(hv[s], 2), a0, false); \
      a0 = __builtin_amdgcn_fdot2(H2X(w8[0][s], 3), H2X(hv[s], 3), a0, false); \
      a1 = __builtin_amdgcn_fdot2(H2X(w8[1][s], 0), H2X(hv[s], 0), a1, false); \
      a1 = __builtin_amdgcn_fdot2(H2X(w8[1][s], 1), H2X(hv[s], 1), a1, false); \
      a1 = __builtin_amdgcn_fdot2(H2X(w8[1][s], 2), H2X(hv[s], 2), a1, false); \
      a1 = __builtin_amdgcn_fdot2(H2X(w8[1][s], 3), H2X(hv[s], 3), a1, false); \
      a2 = __builtin_amdgcn_fdot2(H2X(w8[2][s], 0), H2X(hv[s], 0), a2, false); \
      a2 = __builtin_amdgcn_fdot2(H2X(w8[2][s], 1), H2X(hv[s], 1), a2, false); \
      a2 = __builtin_amdgcn_fdot2(H2X(w8[2][s], 2), H2X(hv[s], 2), a2, false); \
      a2 = __builtin_amdgcn_fdot2(H2X(w8[2][s], 3), H2X(hv[s], 3), a2, false); \
      a3 = __builtin_amdgcn_fdot2(H2X(w8[3][s], 0), H2X(hv[s], 0), a3, false); \
      a3 = __builtin_amdgcn_fdot2(H2X(w8[3][s], 1), H2X(hv[s], 1), a3, false); \
      a3 = __builtin_amdgcn_fdot2(H2X(w8[3][s], 2), H2X(hv[s], 2), a3, false); \
      a3 = __builtin_amdgcn_fdot2(H2X(w8[3][s], 3), H2X(hv[s], 3), a3, false); \
    }                                                                          \
    /* reduce-scatter: lanes {l,l^1} end with full sum of index (l>>1)&3 */    \
    float r0 = kA ? a0 : a2;   /* stage A: XOR7, keep bit1==kA */              \
    float r1 = kA ? a1 : a3;                                                   \
    float b0 = (kA ? a2 : a0) + dpp_mov<0x141>(r0);                            \
    float b1 = (kA ? a3 : a1) + dpp_mov<0x141>(r1);                            \
    float rB = kB ? b0 : b1;   /* stage B: XOR2, keep bit0==kB */              \
    float c  = (kB ? b1 : b0) + dpp_mov<0x4E>(rB);                             \
    float fin = c + dpp_mov<0xB1>(c);   /* stage C: XOR1 all-reduce */         \
    float y = fmaxf(fin + (XQ), 0.f);                                          \
    outp[(long)t * HID] = y;                                                   \
    *(half_t*)(hraw[((U) & 1) ^ 1] + hwb) = (half_t)y;                         \
    XQ = xnew;                                                                 \
    RNN_BAR();                                                                 \
  }

__global__ __launch_bounds__(512, 1) void rnn_kernel(
    const float* __restrict__ Whh, float* __restrict__ out, int T)
{
  // 8 chunks x (64B data + 16B pad), double buffered
  __shared__ alignas(128) unsigned char hraw[2][8 * 80];

  const int tid = threadIdx.x;
  const int l   = tid & 63;
  const int w   = tid >> 6;                // wave 0..7
  const int g   = l & 7;                   // K-chunk: columns [32g, 32g+32)
  const int j0  = w * 32 + (l >> 3) * 4;   // partial rows [j0, j0+4)
  const int rb  = g * 80;                  // LDS read base (bytes)
  const int jown = j0 + ((l >> 1) & 3);    // output row OWNED post-reduce
  const int hwb = ((jown >> 5) * 80 + (jown & 31) * 2);  // LDS write byte
  const bool kA = (l & 4) != 0;
  const bool kB = (l & 2) != 0;
  float* outp = out + (long)blockIdx.x * SEQT * HID + jown;

  // W_hh[j0+i][32g + 8s .. +8] -> w8[i][s]  (64 VGPRs, static indexing)
  half8_t w8[4][4];
  #pragma unroll
  for (int i = 0; i < 4; ++i) {
    const float* wr = Whh + (long)(j0 + i) * HID + g * 32;
    #pragma unroll
    for (int s = 0; s < 4; ++s) {
      float4_t v0 = *(const float4_t*)(wr + s * 8);
      float4_t v1 = *(const float4_t*)(wr + s * 8 + 4);
      w8[i][s] = cvt8(v0, v1);
    }
  }

  // h_0 = 0 (covers data+pads of buffer 0)
  if (tid < 160) ((float*)hraw[0])[tid] = 0.f;

  // 4-deep xp prefetch (named registers -> static indexing), all lanes
  float xq0 = outp[0L * HID];
  float xq1 = outp[1L * HID];
  float xq2 = outp[2L * HID];
  float xq3 = outp[3L * HID];
  RNN_BAR();

  #pragma unroll 1
  for (int t4 = 0; t4 < T; t4 += 4) {
    RNN_STEP(0, xq0)
    RNN_STEP(1, xq1)
    RNN_STEP(2, xq2)
    RNN_STEP(3, xq3)
  }
}

extern "C" void kernel_launch(void* const* d_in, const int* in_sizes, int n_in,
                              void* d_out, int out_size, void* d_ws, size_t ws_size,
                              hipStream_t stream) {
  const float* x   = (const float*)d_in[0];
  const float* Wxh = (const float*)d_in[1];
  const float* Whh = (const float*)d_in[2];
  const float* bh  = (const float*)d_in[3];
  float* out = (float*)d_out;

  if (ws_size >= (size_t)(DIM * HID * sizeof(half_t))) {
    half_t* Wh = (half_t*)d_ws;
    cvt_w_kernel<<<dim3((DIM * HID) / 1024), dim3(256), 0, stream>>>(Wxh, Wh);
    xproj_f16_v2<<<dim3((BATCH * SEQT) / 128), dim3(256), 0, stream>>>(x, Wh, bh, out);
  } else {
    xproj_kernel<<<dim3((BATCH * SEQT) / 64), dim3(256), 0, stream>>>(x, Wxh, bh, out);
  }
  rnn_kernel<<<dim3(BATCH), dim3(512), 0, stream>>>(Whh, out, SEQT);
}

// Round 15
// 891.099 us; speedup vs baseline: 34.4840x; 1.0556x over previous
//
#include <hip/hip_runtime.h>

#define BATCH 64
#define SEQT  2048
#define DIM   256   // INPUT_SIZE
#define HID   256   // HIDDEN_SIZE
#define NSEG  16
#define SEGT  128   // timesteps per xproj segment block

typedef _Float16 half_t;
typedef _Float16 half2_t __attribute__((ext_vector_type(2)));
typedef _Float16 half4_t __attribute__((ext_vector_type(4)));
typedef _Float16 half8_t __attribute__((ext_vector_type(8)));
typedef float    float4_t __attribute__((ext_vector_type(4)));

__device__ __forceinline__ half8_t cvt8(float4_t a, float4_t b) {
  half8_t r;
  r[0] = (half_t)a[0]; r[1] = (half_t)a[1]; r[2] = (half_t)a[2]; r[3] = (half_t)a[3];
  r[4] = (half_t)b[0]; r[5] = (half_t)b[1]; r[6] = (half_t)b[2]; r[7] = (half_t)b[7-7+4];
  r[5] = (half_t)b[1]; r[6] = (half_t)b[2]; r[7] = (half_t)b[3];
  r[4] = (half_t)b[0];
  return r;
}
// extract half2 #c from a half8 (c MUST be a parse-time literal)
#define H2X(v, c) __builtin_shufflevector((v), (v), 2*(c), 2*(c)+1)

// DPP lane-move (pure VALU).  0xB1 = quad_perm lane^1; 0x4E = quad_perm
// lane^2; 0x141 = row_half_mirror (XOR7 within 8).
template<int CTRL>
__device__ __forceinline__ float dpp_mov(float a) {
  int t = __builtin_amdgcn_mov_dpp(__builtin_bit_cast(int, a), CTRL, 0xF, 0xF, true);
  return __builtin_bit_cast(float, t);
}

#define RNN_BAR() asm volatile("s_waitcnt lgkmcnt(0)\n\ts_barrier" ::: "memory")

// producer->consumer flag poll: lane 0 acquires (agent scope -> L1/L2 inv),
// block barrier propagates visibility to all waves of the block.
__device__ __forceinline__ void poll_flag(const unsigned int* f) {
  if (threadIdx.x == 0) {
    while (__hip_atomic_load(f, __ATOMIC_ACQUIRE, __HIP_MEMORY_SCOPE_AGENT) == 0u)
      __builtin_amdgcn_s_sleep(2);
  }
  __syncthreads();
}

// ---------------------------------------------------------------------------
// prep: W_xh fp32 -> f16 into d_ws[0..128KB); block 0 also zeros the 1024
// chain x segment flags at d_ws[128KB..+4KB).
// ---------------------------------------------------------------------------
__global__ __launch_bounds__(256) void prep_kernel(
    const float* __restrict__ W, half_t* __restrict__ Wh,
    unsigned int* __restrict__ flags)
{
  const int i = (blockIdx.x * 256 + threadIdx.x) * 4;
  float4_t v = *(const float4_t*)(W + i);
  half4_t o; o[0]=(half_t)v[0]; o[1]=(half_t)v[1]; o[2]=(half_t)v[2]; o[3]=(half_t)v[3];
  *(half4_t*)(Wh + i) = o;
  if (blockIdx.x == 0) {
    flags[threadIdx.x]       = 0u;
    flags[threadIdx.x + 256] = 0u;
    flags[threadIdx.x + 512] = 0u;
    flags[threadIdx.x + 768] = 0u;
  }
}

// ---------------------------------------------------------------------------
// v6 rnn step (byte-equivalent math to the verified 851us kernel)
// ---------------------------------------------------------------------------
#define RNN_STEP(U, XQ)                                                        \
  {                                                                            \
    const int t = t4 + (U);                                                    \
    const int tp = (t + 4 < T) ? (t + 4) : (T - 1);                            \
    float xnew = outp[(long)tp * HID];                                         \
    half8_t hv[4];                                                             \
    _Pragma("unroll")                                                          \
    for (int s = 0; s < 4; ++s)                                                \
      hv[s] = *(const half8_t*)(hraw[(U) & 1] + rb + 16 * s);                  \
    float a0 = 0.f, a1 = 0.f, a2 = 0.f, a3 = 0.f;                              \
    _Pragma("unroll")                                                          \
    for (int s = 0; s < 4; ++s) {                                              \
      a0 = __builtin_amdgcn_fdot2(H2X(w8[0][s], 0), H2X(hv[s], 0), a0, false); \
      a0 = __builtin_amdgcn_fdot2(H2X(w8[0][s], 1), H2X(hv[s], 1), a0, false); \
      a0 = __builtin_amdgcn_fdot2(H2X(w8[0][s], 2), H2X(hv[s], 2), a0, false); \
      a0 = __builtin_amdgcn_fdot2(H2X(w8[0][s], 3), H2X(hv[s], 3), a0, false); \
      a1 = __builtin_amdgcn_fdot2(H2X(w8[1][s], 0), H2X(hv[s], 0), a1, false); \
      a1 = __builtin_amdgcn_fdot2(H2X(w8[1][s], 1), H2X(hv[s], 1), a1, false); \
      a1 = __builtin_amdgcn_fdot2(H2X(w8[1][s], 2), H2X(hv[s], 2), a1, false); \
      a1 = __builtin_amdgcn_fdot2(H2X(w8[1][s], 3), H2X(hv[s], 3), a1, false); \
      a2 = __builtin_amdgcn_fdot2(H2X(w8[2][s], 0), H2X(hv[s], 0), a2, false); \
      a2 = __builtin_amdgcn_fdot2(H2X(w8[2][s], 1), H2X(hv[s], 1), a2, false); \
      a2 = __builtin_amdgcn_fdot2(H2X(w8[2][s], 2), H2X(hv[s], 2), a2, false); \
      a2 = __builtin_amdgcn_fdot2(H2X(w8[2][s], 3), H2X(hv[s], 3), a2, false); \
      a3 = __builtin_amdgcn_fdot2(H2X(w8[3][s], 0), H2X(hv[s], 0), a3, false); \
      a3 = __builtin_amdgcn_fdot2(H2X(w8[3][s], 1), H2X(hv[s], 1), a3, false); \
      a3 = __builtin_amdgcn_fdot2(H2X(w8[3][s], 2), H2X(hv[s], 2), a3, false); \
      a3 = __builtin_amdgcn_fdot2(H2X(w8[3][s], 3), H2X(hv[s], 3), a3, false); \
    }                                                                          \
    float r0 = kA ? a0 : a2;                                                   \
    float r1 = kA ? a1 : a3;                                                   \
    float b0 = (kA ? a2 : a0) + dpp_mov<0x141>(r0);                            \
    float b1 = (kA ? a3 : a1) + dpp_mov<0x141>(r1);                            \
    float rB = kB ? b0 : b1;                                                   \
    float c  = (kB ? b1 : b0) + dpp_mov<0x4E>(rB);                             \
    float fin = c + dpp_mov<0xB1>(c);                                          \
    float y = fmaxf(fin + (XQ), 0.f);                                          \
    outp[(long)t * HID] = y;                                                   \
    *(half_t*)(hraw[((U) & 1) ^ 1] + hwb) = (half_t)y;                         \
    XQ = xnew;                                                                 \
    RNN_BAR();                                                                 \
  }

// ---------------------------------------------------------------------------
// FUSED kernel, grid 1088 x 512:
//   blocks 0..63    : rnn chain (v6 structure) gated by per-segment flags
//   blocks 64..1087 : xproj tile (seg k = (b-64)>>6, chain c = (b-64)&63),
//                     segment-major so every chain's seg 0 lands first.
// ---------------------------------------------------------------------------
__global__ __launch_bounds__(512, 1) void fused_kernel(
    const float* __restrict__ x, const half_t* __restrict__ Wxh16,
    const float* __restrict__ Whh, const float* __restrict__ bh,
    float* __restrict__ out, unsigned int* __restrict__ flags, int T)
{
  if (blockIdx.x >= 64) {
    // ================= xproj producer =================
    const int b = blockIdx.x - 64;
    const int k = b >> 6;        // segment
    const int c = b & 63;        // chain
    const int lane = threadIdx.x & 63;
    const int w = threadIdx.x >> 6;    // 0..7, owns n-tiles 2w, 2w+1
    const int r16 = lane & 15;
    const int kg = lane >> 4;
    const long m0 = ((long)c * NSEG + k) * SEGT;   // global row base

    half8_t bfr[2][8];
    float bb[2];
    #pragma unroll
    for (int i = 0; i < 2; ++i) {
      const int nt = w * 2 + i;
      const half_t* wr = Wxh16 + (nt * 16 + r16) * (long)DIM + kg * 8;
      #pragma unroll
      for (int kf = 0; kf < 8; ++kf)
        bfr[i][kf] = *(const half8_t*)(wr + kf * 32);
      bb[i] = bh[nt * 16 + r16];
    }
    #pragma unroll 1
    for (int mi = 0; mi < 8; ++mi) {
      const long mrow = m0 + mi * 16;
      half8_t a[8];
      const float* xr = x + (mrow + r16) * (long)DIM + kg * 8;
      #pragma unroll
      for (int kf = 0; kf < 8; ++kf) {
        float4_t x0 = *(const float4_t*)(xr + kf * 32);
        float4_t x1 = *(const float4_t*)(xr + kf * 32 + 4);
        a[kf] = cvt8(x0, x1);
      }
      #pragma unroll
      for (int i = 0; i < 2; ++i) {
        float4_t acc = {bb[i], bb[i], bb[i], bb[i]};
        #pragma unroll
        for (int kf = 0; kf < 8; ++kf)
          acc = __builtin_amdgcn_mfma_f32_16x16x32_f16(a[kf], bfr[i][kf], acc, 0, 0, 0);
        float* op = out + (mrow + kg * 4) * (long)HID + (w * 2 + i) * 16 + r16;
        #pragma unroll
        for (int r = 0; r < 4; ++r) op[(long)r * HID] = acc[r];
      }
    }
    __syncthreads();   // drains vmcnt(0): all block stores complete
    if (threadIdx.x == 0)
      __hip_atomic_store(flags + ((c << 4) | k), 1u, __ATOMIC_RELEASE,
                         __HIP_MEMORY_SCOPE_AGENT);
    return;
  }

  // ================= rnn consumer (v6 @851us) =================
  __shared__ alignas(128) unsigned char hraw[2][8 * 80];

  const int chain = blockIdx.x;
  const int tid = threadIdx.x;
  const int l   = tid & 63;
  const int w   = tid >> 6;                // wave 0..7
  const int g   = l & 7;                   // K-chunk: columns [32g, 32g+32)
  const int j0  = w * 32 + (l >> 3) * 4;   // partial rows [j0, j0+4)
  const int rb  = g * 80;                  // LDS read base (bytes)
  const int jown = j0 + ((l >> 1) & 3);    // output row OWNED post-reduce
  const int hwb = ((jown >> 5) * 80 + (jown & 31) * 2);  // LDS write byte
  const bool kA = (l & 4) != 0;
  const bool kB = (l & 2) != 0;
  const unsigned int* fl = flags + (chain << 4);
  float* outp = out + (long)chain * SEQT * HID + jown;

  // W_hh[j0+i][32g + 8s .. +8] -> w8[i][s]  (64 VGPRs, static indexing)
  half8_t w8[4][4];
  #pragma unroll
  for (int i = 0; i < 4; ++i) {
    const float* wr = Whh + (long)(j0 + i) * HID + g * 32;
    #pragma unroll
    for (int s = 0; s < 4; ++s) {
      float4_t v0 = *(const float4_t*)(wr + s * 8);
      float4_t v1 = *(const float4_t*)(wr + s * 8 + 4);
      w8[i][s] = cvt8(v0, v1);
    }
  }

  // h_0 = 0 (covers data+pads of buffer 0)
  if (tid < 160) ((float*)hraw[0])[tid] = 0.f;

  // wait for segment 0, then 4-deep xp prefetch (t = 0..3, all in seg 0)
  poll_flag(fl + 0);
  float xq0 = outp[0L * HID];
  float xq1 = outp[1L * HID];
  float xq2 = outp[2L * HID];
  float xq3 = outp[3L * HID];
  RNN_BAR();

  #pragma unroll 1
  for (int seg = 0; seg < NSEG; ++seg) {
    // loads issued during seg touch up to t = 128*seg+127+4 -> seg+1
    const int ps = (seg + 1 < NSEG) ? (seg + 1) : (NSEG - 1);
    poll_flag(fl + ps);
    const int tend = seg * SEGT + SEGT;
    #pragma unroll 1
    for (int t4 = seg * SEGT; t4 < tend; t4 += 4) {
      RNN_STEP(0, xq0)
      RNN_STEP(1, xq1)
      RNN_STEP(2, xq2)
      RNN_STEP(3, xq3)
    }
  }
}

// ===========================================================================
// FALLBACK (ws too small for Wh+flags): round-13 path, proven @940us
// ===========================================================================
__global__ __launch_bounds__(256) void xproj_kernel(
    const float* __restrict__ x, const float* __restrict__ Wxh,
    const float* __restrict__ bh, float* __restrict__ out)
{
  const int lane = threadIdx.x & 63;
  const int wave = threadIdx.x >> 6;
  const int r16  = lane & 15;
  const int kg   = lane >> 4;
  const long m0  = (long)blockIdx.x * 64 + wave * 16;

  half8_t a[8];
  const float* xr = x + (m0 + r16) * (long)DIM + kg * 8;
  #pragma unroll
  for (int kf = 0; kf < 8; ++kf) {
    float4_t x0 = *(const float4_t*)(xr + kf * 32);
    float4_t x1 = *(const float4_t*)(xr + kf * 32 + 4);
    a[kf] = cvt8(x0, x1);
  }
  for (int nt = 0; nt < 16; ++nt) {
    const float* wr = Wxh + (nt * 16 + r16) * (long)DIM + kg * 8;
    float bb = bh[nt * 16 + r16];
    float4_t acc = {bb, bb, bb, bb};
    #pragma unroll
    for (int kf = 0; kf < 8; ++kf) {
      float4_t w0 = *(const float4_t*)(wr + kf * 32);
      float4_t w1 = *(const float4_t*)(wr + kf * 32 + 4);
      acc = __builtin_amdgcn_mfma_f32_16x16x32_f16(a[kf], cvt8(w0, w1), acc, 0, 0, 0);
    }
    float* op = out + (m0 + kg * 4) * (long)HID + nt * 16 + r16;
    #pragma unroll
    for (int r = 0; r < 4; ++r) op[(long)r * HID] = acc[r];
  }
}

__global__ __launch_bounds__(512, 1) void rnn_kernel(
    const float* __restrict__ Whh, float* __restrict__ out, int T)
{
  __shared__ alignas(128) unsigned char hraw[2][8 * 80];

  const int tid = threadIdx.x;
  const int l   = tid & 63;
  const int w   = tid >> 6;
  const int g   = l & 7;
  const int j0  = w * 32 + (l >> 3) * 4;
  const int rb  = g * 80;
  const int jown = j0 + ((l >> 1) & 3);
  const int hwb = ((jown >> 5) * 80 + (jown & 31) * 2);
  const bool kA = (l & 4) != 0;
  const bool kB = (l & 2) != 0;
  float* outp = out + (long)blockIdx.x * SEQT * HID + jown;

  half8_t w8[4][4];
  #pragma unroll
  for (int i = 0; i < 4; ++i) {
    const float* wr = Whh + (long)(j0 + i) * HID + g * 32;
    #pragma unroll
    for (int s = 0; s < 4; ++s) {
      float4_t v0 = *(const float4_t*)(wr + s * 8);
      float4_t v1 = *(const float4_t*)(wr + s * 8 + 4);
      w8[i][s] = cvt8(v0, v1);
    }
  }
  if (tid < 160) ((float*)hraw[0])[tid] = 0.f;

  float xq0 = outp[0L * HID];
  float xq1 = outp[1L * HID];
  float xq2 = outp[2L * HID];
  float xq3 = outp[3L * HID];
  RNN_BAR();

  #pragma unroll 1
  for (int t4 = 0; t4 < T; t4 += 4) {
    RNN_STEP(0, xq0)
    RNN_STEP(1, xq1)
    RNN_STEP(2, xq2)
    RNN_STEP(3, xq3)
  }
}

// ===========================================================================
extern "C" void kernel_launch(void* const* d_in, const int* in_sizes, int n_in,
                              void* d_out, int out_size, void* d_ws, size_t ws_size,
                              hipStream_t stream) {
  const float* x   = (const float*)d_in[0];
  const float* Wxh = (const float*)d_in[1];
  const float* Whh = (const float*)d_in[2];
  const float* bh  = (const float*)d_in[3];
  float* out = (float*)d_out;

  const size_t wh_bytes = (size_t)DIM * HID * sizeof(half_t);   // 128 KB
  const size_t need = wh_bytes + 4096;                          // + flags

  if (ws_size >= need) {
    half_t* Wh = (half_t*)d_ws;
    unsigned int* flags = (unsigned int*)((char*)d_ws + wh_bytes);
    prep_kernel<<<dim3((DIM * HID) / 1024), dim3(256), 0, stream>>>(Wxh, Wh, flags);
    fused_kernel<<<dim3(64 + BATCH * NSEG), dim3(512), 0, stream>>>(
        x, Wh, Whh, bh, out, flags, SEQT);
  } else {
    xproj_kernel<<<dim3((BATCH * SEQT) / 64), dim3(256), 0, stream>>>(x, Wxh, bh, out);
    rnn_kernel<<<dim3(BATCH), dim3(512), 0, stream>>>(Whh, out, SEQT);
  }
}

// Round 16
// 888.346 us; speedup vs baseline: 34.5909x; 1.0031x over previous
//
#include <hip/hip_runtime.h>

#define BATCH 64
#define SEQT  2048
#define DIM   256   // INPUT_SIZE
#define HID   256   // HIDDEN_SIZE
#define NSEG  16
#define SEGT  128   // timesteps per xproj segment block

typedef _Float16 half_t;
typedef _Float16 half2_t __attribute__((ext_vector_type(2)));
typedef _Float16 half4_t __attribute__((ext_vector_type(4)));
typedef _Float16 half8_t __attribute__((ext_vector_type(8)));
typedef float    float4_t __attribute__((ext_vector_type(4)));

__device__ __forceinline__ half8_t cvt8(float4_t a, float4_t b) {
  half8_t r;
  r[0] = (half_t)a[0]; r[1] = (half_t)a[1]; r[2] = (half_t)a[2]; r[3] = (half_t)a[3];
  r[4] = (half_t)b[0]; r[5] = (half_t)b[1]; r[6] = (half_t)b[2]; r[7] = (half_t)b[3];
  return r;
}
// extract half2 #c from a half8 (c MUST be a parse-time literal)
#define H2X(v, c) __builtin_shufflevector((v), (v), 2*(c), 2*(c)+1)

// DPP lane-move (pure VALU).  0xB1 = quad_perm lane^1; 0x4E = quad_perm
// lane^2; 0x141 = row_half_mirror (XOR7 within 8).
template<int CTRL>
__device__ __forceinline__ float dpp_mov(float a) {
  int t = __builtin_amdgcn_mov_dpp(__builtin_bit_cast(int, a), CTRL, 0xF, 0xF, true);
  return __builtin_bit_cast(float, t);
}

#define RNN_BAR() asm volatile("s_waitcnt lgkmcnt(0)\n\ts_barrier" ::: "memory")

// producer->consumer flag poll: lane 0 acquires (agent scope -> L1/L2 inv),
// block barrier propagates visibility to all waves of the block.
__device__ __forceinline__ void poll_flag(const unsigned int* f) {
  if (threadIdx.x == 0) {
    while (__hip_atomic_load(f, __ATOMIC_ACQUIRE, __HIP_MEMORY_SCOPE_AGENT) == 0u)
      __builtin_amdgcn_s_sleep(2);
  }
  __syncthreads();
}

// ---------------------------------------------------------------------------
// prep: W_xh fp32 -> f16 into d_ws[0..128KB); block 0 also zeros the 1024
// chain x segment flags at d_ws[128KB..+4KB).
// ---------------------------------------------------------------------------
__global__ __launch_bounds__(256) void prep_kernel(
    const float* __restrict__ W, half_t* __restrict__ Wh,
    unsigned int* __restrict__ flags)
{
  const int i = (blockIdx.x * 256 + threadIdx.x) * 4;
  float4_t v = *(const float4_t*)(W + i);
  half4_t o; o[0]=(half_t)v[0]; o[1]=(half_t)v[1]; o[2]=(half_t)v[2]; o[3]=(half_t)v[3];
  *(half4_t*)(Wh + i) = o;
  if (blockIdx.x == 0) {
    flags[threadIdx.x]       = 0u;
    flags[threadIdx.x + 256] = 0u;
    flags[threadIdx.x + 512] = 0u;
    flags[threadIdx.x + 768] = 0u;
  }
}

// ---------------------------------------------------------------------------
// v6 rnn step (byte-equivalent math to the verified 851us kernel)
// ---------------------------------------------------------------------------
#define RNN_STEP(U, XQ)                                                        \
  {                                                                            \
    const int t = t4 + (U);                                                    \
    const int tp = (t + 4 < T) ? (t + 4) : (T - 1);                            \
    float xnew = outp[(long)tp * HID];                                         \
    half8_t hv[4];                                                             \
    _Pragma("unroll")                                                          \
    for (int s = 0; s < 4; ++s)                                                \
      hv[s] = *(const half8_t*)(hraw[(U) & 1] + rb + 16 * s);                  \
    float a0 = 0.f, a1 = 0.f, a2 = 0.f, a3 = 0.f;                              \
    _Pragma("unroll")                                                          \
    for (int s = 0; s < 4; ++s) {                                              \
      a0 = __builtin_amdgcn_fdot2(H2X(w8[0][s], 0), H2X(hv[s], 0), a0, false); \
      a0 = __builtin_amdgcn_fdot2(H2X(w8[0][s], 1), H2X(hv[s], 1), a0, false); \
      a0 = __builtin_amdgcn_fdot2(H2X(w8[0][s], 2), H2X(hv[s], 2), a0, false); \
      a0 = __builtin_amdgcn_fdot2(H2X(w8[0][s], 3), H2X(hv[s], 3), a0, false); \
      a1 = __builtin_amdgcn_fdot2(H2X(w8[1][s], 0), H2X(hv[s], 0), a1, false); \
      a1 = __builtin_amdgcn_fdot2(H2X(w8[1][s], 1), H2X(hv[s], 1), a1, false); \
      a1 = __builtin_amdgcn_fdot2(H2X(w8[1][s], 2), H2X(hv[s], 2), a1, false); \
      a1 = __builtin_amdgcn_fdot2(H2X(w8[1][s], 3), H2X(hv[s], 3), a1, false); \
      a2 = __builtin_amdgcn_fdot2(H2X(w8[2][s], 0), H2X(hv[s], 0), a2, false); \
      a2 = __builtin_amdgcn_fdot2(H2X(w8[2][s], 1), H2X(hv[s], 1), a2, false); \
      a2 = __builtin_amdgcn_fdot2(H2X(w8[2][s], 2), H2X(hv[s], 2), a2, false); \
      a2 = __builtin_amdgcn_fdot2(H2X(w8[2][s], 3), H2X(hv[s], 3), a2, false); \
      a3 = __builtin_amdgcn_fdot2(H2X(w8[3][s], 0), H2X(hv[s], 0), a3, false); \
      a3 = __builtin_amdgcn_fdot2(H2X(w8[3][s], 1), H2X(hv[s], 1), a3, false); \
      a3 = __builtin_amdgcn_fdot2(H2X(w8[3][s], 2), H2X(hv[s], 2), a3, false); \
      a3 = __builtin_amdgcn_fdot2(H2X(w8[3][s], 3), H2X(hv[s], 3), a3, false); \
    }                                                                          \
    float r0 = kA ? a0 : a2;                                                   \
    float r1 = kA ? a1 : a3;                                                   \
    float b0 = (kA ? a2 : a0) + dpp_mov<0x141>(r0);                            \
    float b1 = (kA ? a3 : a1) + dpp_mov<0x141>(r1);                            \
    float rB = kB ? b0 : b1;                                                   \
    float c  = (kB ? b1 : b0) + dpp_mov<0x4E>(rB);                             \
    float fin = c + dpp_mov<0xB1>(c);                                          \
    float y = fmaxf(fin + (XQ), 0.f);                                          \
    outp[(long)t * HID] = y;                                                   \
    *(half_t*)(hraw[((U) & 1) ^ 1] + hwb) = (half_t)y;                         \
    XQ = xnew;                                                                 \
    RNN_BAR();                                                                 \
  }

// ---------------------------------------------------------------------------
// FUSED kernel, grid 1088 x 512:
//   blocks 0..63    : rnn chain (v6 structure) gated by per-segment flags,
//                     waves at PRIORITY 3 (CU scheduler favors them over any
//                     co-resident producer waves -> producers only steal
//                     issue slots where the rnn is stalled anyway)
//   blocks 64..1087 : xproj tile (seg k = (b-64)>>6, chain c = (b-64)&63),
//                     segment-major so every chain's seg 0 lands first;
//                     default priority 0.
// ---------------------------------------------------------------------------
__global__ __launch_bounds__(512, 1) void fused_kernel(
    const float* __restrict__ x, const half_t* __restrict__ Wxh16,
    const float* __restrict__ Whh, const float* __restrict__ bh,
    float* __restrict__ out, unsigned int* __restrict__ flags, int T)
{
  if (blockIdx.x >= 64) {
    // ================= xproj producer (prio 0) =================
    const int b = blockIdx.x - 64;
    const int k = b >> 6;        // segment
    const int c = b & 63;        // chain
    const int lane = threadIdx.x & 63;
    const int w = threadIdx.x >> 6;    // 0..7, owns n-tiles 2w, 2w+1
    const int r16 = lane & 15;
    const int kg = lane >> 4;
    const long m0 = ((long)c * NSEG + k) * SEGT;   // global row base

    half8_t bfr[2][8];
    float bb[2];
    #pragma unroll
    for (int i = 0; i < 2; ++i) {
      const int nt = w * 2 + i;
      const half_t* wr = Wxh16 + (nt * 16 + r16) * (long)DIM + kg * 8;
      #pragma unroll
      for (int kf = 0; kf < 8; ++kf)
        bfr[i][kf] = *(const half8_t*)(wr + kf * 32);
      bb[i] = bh[nt * 16 + r16];
    }
    #pragma unroll 1
    for (int mi = 0; mi < 8; ++mi) {
      const long mrow = m0 + mi * 16;
      half8_t a[8];
      const float* xr = x + (mrow + r16) * (long)DIM + kg * 8;
      #pragma unroll
      for (int kf = 0; kf < 8; ++kf) {
        float4_t x0 = *(const float4_t*)(xr + kf * 32);
        float4_t x1 = *(const float4_t*)(xr + kf * 32 + 4);
        a[kf] = cvt8(x0, x1);
      }
      #pragma unroll
      for (int i = 0; i < 2; ++i) {
        float4_t acc = {bb[i], bb[i], bb[i], bb[i]};
        #pragma unroll
        for (int kf = 0; kf < 8; ++kf)
          acc = __builtin_amdgcn_mfma_f32_16x16x32_f16(a[kf], bfr[i][kf], acc, 0, 0, 0);
        float* op = out + (mrow + kg * 4) * (long)HID + (w * 2 + i) * 16 + r16;
        #pragma unroll
        for (int r = 0; r < 4; ++r) op[(long)r * HID] = acc[r];
      }
    }
    __syncthreads();   // drains vmcnt(0): all block stores complete
    if (threadIdx.x == 0)
      __hip_atomic_store(flags + ((c << 4) | k), 1u, __ATOMIC_RELEASE,
                         __HIP_MEMORY_SCOPE_AGENT);
    return;
  }

  // ================= rnn consumer (v6 @851us, prio 3) =================
  __builtin_amdgcn_s_setprio(3);   // persistent wave priority: beat producers

  __shared__ alignas(128) unsigned char hraw[2][8 * 80];

  const int chain = blockIdx.x;
  const int tid = threadIdx.x;
  const int l   = tid & 63;
  const int w   = tid >> 6;                // wave 0..7
  const int g   = l & 7;                   // K-chunk: columns [32g, 32g+32)
  const int j0  = w * 32 + (l >> 3) * 4;   // partial rows [j0, j0+4)
  const int rb  = g * 80;                  // LDS read base (bytes)
  const int jown = j0 + ((l >> 1) & 3);    // output row OWNED post-reduce
  const int hwb = ((jown >> 5) * 80 + (jown & 31) * 2);  // LDS write byte
  const bool kA = (l & 4) != 0;
  const bool kB = (l & 2) != 0;
  const unsigned int* fl = flags + (chain << 4);
  float* outp = out + (long)chain * SEQT * HID + jown;

  // W_hh[j0+i][32g + 8s .. +8] -> w8[i][s]  (64 VGPRs, static indexing)
  half8_t w8[4][4];
  #pragma unroll
  for (int i = 0; i < 4; ++i) {
    const float* wr = Whh + (long)(j0 + i) * HID + g * 32;
    #pragma unroll
    for (int s = 0; s < 4; ++s) {
      float4_t v0 = *(const float4_t*)(wr + s * 8);
      float4_t v1 = *(const float4_t*)(wr + s * 8 + 4);
      w8[i][s] = cvt8(v0, v1);
    }
  }

  // h_0 = 0 (covers data+pads of buffer 0)
  if (tid < 160) ((float*)hraw[0])[tid] = 0.f;

  // wait for segment 0, then 4-deep xp prefetch (t = 0..3, all in seg 0)
  poll_flag(fl + 0);
  float xq0 = outp[0L * HID];
  float xq1 = outp[1L * HID];
  float xq2 = outp[2L * HID];
  float xq3 = outp[3L * HID];
  RNN_BAR();

  #pragma unroll 1
  for (int seg = 0; seg < NSEG; ++seg) {
    // loads issued during seg touch up to t = 128*seg+127+4 -> seg+1
    const int ps = (seg + 1 < NSEG) ? (seg + 1) : (NSEG - 1);
    poll_flag(fl + ps);
    const int tend = seg * SEGT + SEGT;
    #pragma unroll 1
    for (int t4 = seg * SEGT; t4 < tend; t4 += 4) {
      RNN_STEP(0, xq0)
      RNN_STEP(1, xq1)
      RNN_STEP(2, xq2)
      RNN_STEP(3, xq3)
    }
  }
}

// ===========================================================================
// FALLBACK (ws too small for Wh+flags): round-13 path, proven @940us
// ===========================================================================
__global__ __launch_bounds__(256) void xproj_kernel(
    const float* __restrict__ x, const float* __restrict__ Wxh,
    const float* __restrict__ bh, float* __restrict__ out)
{
  const int lane = threadIdx.x & 63;
  const int wave = threadIdx.x >> 6;
  const int r16  = lane & 15;
  const int kg   = lane >> 4;
  const long m0  = (long)blockIdx.x * 64 + wave * 16;

  half8_t a[8];
  const float* xr = x + (m0 + r16) * (long)DIM + kg * 8;
  #pragma unroll
  for (int kf = 0; kf < 8; ++kf) {
    float4_t x0 = *(const float4_t*)(xr + kf * 32);
    float4_t x1 = *(const float4_t*)(xr + kf * 32 + 4);
    a[kf] = cvt8(x0, x1);
  }
  for (int nt = 0; nt < 16; ++nt) {
    const float* wr = Wxh + (nt * 16 + r16) * (long)DIM + kg * 8;
    float bb = bh[nt * 16 + r16];
    float4_t acc = {bb, bb, bb, bb};
    #pragma unroll
    for (int kf = 0; kf < 8; ++kf) {
      float4_t w0 = *(const float4_t*)(wr + kf * 32);
      float4_t w1 = *(const float4_t*)(wr + kf * 32 + 4);
      acc = __builtin_amdgcn_mfma_f32_16x16x32_f16(a[kf], cvt8(w0, w1), acc, 0, 0, 0);
    }
    float* op = out + (m0 + kg * 4) * (long)HID + nt * 16 + r16;
    #pragma unroll
    for (int r = 0; r < 4; ++r) op[(long)r * HID] = acc[r];
  }
}

__global__ __launch_bounds__(512, 1) void rnn_kernel(
    const float* __restrict__ Whh, float* __restrict__ out, int T)
{
  __shared__ alignas(128) unsigned char hraw[2][8 * 80];

  const int tid = threadIdx.x;
  const int l   = tid & 63;
  const int w   = tid >> 6;
  const int g   = l & 7;
  const int j0  = w * 32 + (l >> 3) * 4;
  const int rb  = g * 80;
  const int jown = j0 + ((l >> 1) & 3);
  const int hwb = ((jown >> 5) * 80 + (jown & 31) * 2);
  const bool kA = (l & 4) != 0;
  const bool kB = (l & 2) != 0;
  float* outp = out + (long)blockIdx.x * SEQT * HID + jown;

  half8_t w8[4][4];
  #pragma unroll
  for (int i = 0; i < 4; ++i) {
    const float* wr = Whh + (long)(j0 + i) * HID + g * 32;
    #pragma unroll
    for (int s = 0; s < 4; ++s) {
      float4_t v0 = *(const float4_t*)(wr + s * 8);
      float4_t v1 = *(const float4_t*)(wr + s * 8 + 4);
      w8[i][s] = cvt8(v0, v1);
    }
  }
  if (tid < 160) ((float*)hraw[0])[tid] = 0.f;

  float xq0 = outp[0L * HID];
  float xq1 = outp[1L * HID];
  float xq2 = outp[2L * HID];
  float xq3 = outp[3L * HID];
  RNN_BAR();

  #pragma unroll 1
  for (int t4 = 0; t4 < T; t4 += 4) {
    RNN_STEP(0, xq0)
    RNN_STEP(1, xq1)
    RNN_STEP(2, xq2)
    RNN_STEP(3, xq3)
  }
}

// ===========================================================================
extern "C" void kernel_launch(void* const* d_in, const int* in_sizes, int n_in,
                              void* d_out, int out_size, void* d_ws, size_t ws_size,
                              hipStream_t stream) {
  const float* x   = (const float*)d_in[0];
  const float* Wxh = (const float*)d_in[1];
  const float* Whh = (const float*)d_in[2];
  const float* bh  = (const float*)d_in[3];
  float* out = (float*)d_out;

  const size_t wh_bytes = (size_t)DIM * HID * sizeof(half_t);   // 128 KB
  const size_t need = wh_bytes + 4096;                          // + flags

  if (ws_size >= need) {
    half_t* Wh = (half_t*)d_ws;
    unsigned int* flags = (unsigned int*)((char*)d_ws + wh_bytes);
    prep_kernel<<<dim3((DIM * HID) / 1024), dim3(256), 0, stream>>>(Wxh, Wh, flags);
    fused_kernel<<<dim3(64 + BATCH * NSEG), dim3(512), 0, stream>>>(
        x, Wh, Whh, bh, out, flags, SEQT);
  } else {
    xproj_kernel<<<dim3((BATCH * SEQT) / 64), dim3(256), 0, stream>>>(x, Wxh, bh, out);
    rnn_kernel<<<dim3(BATCH), dim3(512), 0, stream>>>(Whh, out, SEQT);
  }
}